// Round 6
// baseline (275.117 us; speedup 1.0000x reference)
//
#include <hip/hip_runtime.h>

#define NNODES 100000
#define NEDGES 1600000
#define DIM 64
#define NB 782          // buckets of 128 nodes (dst >> 7); 782*128 = 100096
#define NPB 512         // partition blocks
#define CHUNK 3125      // edges per partition block (NPB * CHUNK == NEDGES)
#define CAP 4096        // padded slots per bucket (Binomial mean 2046, sigma 45)

// ---------------- P0: init per-bucket cursors to padded bases ---------------
__global__ __launch_bounds__(1024) void init_kernel(int* __restrict__ gcursor) {
  int t = threadIdx.x;
  if (t < NB) gcursor[t] = t * CAP;
}

// ---------------- P1: partition edges into padded buckets -------------------
__global__ __launch_bounds__(1024) void partition_kernel(
    const int* __restrict__ ei, int* __restrict__ gcursor,
    int* __restrict__ bpart) {
  __shared__ int lh[NB];
  __shared__ int cur[NB];
  int t = threadIdx.x;
  for (int b = t; b < NB; b += 1024) lh[b] = 0;
  __syncthreads();
  int base = blockIdx.x * CHUNK;
  for (int i = t; i < CHUNK; i += 1024)
    atomicAdd(&lh[ei[NEDGES + base + i] >> 7], 1);
  __syncthreads();
  for (int b = t; b < NB; b += 1024) {
    int c = lh[b];
    cur[b] = c ? atomicAdd(&gcursor[b], c) : 0;   // reserve contiguous run
  }
  __syncthreads();
  for (int i = t; i < CHUNK; i += 1024) {
    int s = ei[base + i];
    int d = ei[NEDGES + base + i];
    int p = atomicAdd(&cur[d >> 7], 1);
    bpart[p] = ((d & 127) << 17) | s;   // src < 2^17, dlow in bits 17..23
  }
}

// ---------------- P2: per-bucket LDS sort + gather, fused -------------------
// block = one bucket of 128 nodes; sorts (dlow|src) into LDS, then gathers
// x rows straight off the LDS edge list. No CSR ever hits global memory.
__global__ __launch_bounds__(512) void sort_gather_kernel(
    const int* __restrict__ bpart, const int* __restrict__ gcursor,
    const float* __restrict__ x, float* __restrict__ agg) {
  __shared__ int sd[128];     // per-node degree -> inclusive scan
  __shared__ int cur[128];    // scatter cursors
  __shared__ int stage[CAP];  // sorted src list for this bucket
  int b = blockIdx.x;
  int t = threadIdx.x;
  int pbase = b * CAP;
  int cnt = gcursor[b] - pbase;
  if (t < 128) sd[t] = 0;
  __syncthreads();
  for (int i = t; i < cnt; i += 512)
    atomicAdd(&sd[bpart[pbase + i] >> 17], 1);
  __syncthreads();
  int deg = (t < 128) ? sd[t] : 0;
  for (int off = 1; off < 128; off <<= 1) {   // inclusive scan of degrees
    int a = (t < 128 && t >= off) ? sd[t - off] : 0;
    __syncthreads();
    if (t < 128) sd[t] += a;
    __syncthreads();
  }
  if (t < 128) cur[t] = sd[t] - deg;          // exclusive start
  __syncthreads();
  for (int i = t; i < cnt; i += 512) {
    int v = bpart[pbase + i];
    int p = atomicAdd(&cur[v >> 17], 1);
    stage[p] = v & 0x1FFFF;                   // LDS scatter, cheap
  }
  __syncthreads();
  // gather: 32 nodes concurrently x 16 lanes, 4 passes over 128 nodes
  int part = t & 15;
  int ng = t >> 4;                            // 0..31
#pragma unroll 1
  for (int pass = 0; pass < 4; ++pass) {
    int nl = ng + pass * 32;                  // local node 0..127
    int node = b * 128 + nl;
    if (node >= NNODES) continue;
    int e0 = (nl == 0) ? 0 : sd[nl - 1];
    int e1 = sd[nl];
    float4 a0 = make_float4(0.f, 0.f, 0.f, 0.f);
    float4 a1 = a0, a2 = a0, a3 = a0;
    int e = e0;
    for (; e + 4 <= e1; e += 4) {             // 4 independent loads in flight
      int s0 = stage[e + 0];
      int s1 = stage[e + 1];
      int s2 = stage[e + 2];
      int s3 = stage[e + 3];
      float4 v0 = ((const float4*)(x + (size_t)s0 * DIM))[part];
      float4 v1 = ((const float4*)(x + (size_t)s1 * DIM))[part];
      float4 v2 = ((const float4*)(x + (size_t)s2 * DIM))[part];
      float4 v3 = ((const float4*)(x + (size_t)s3 * DIM))[part];
      a0.x += v0.x; a0.y += v0.y; a0.z += v0.z; a0.w += v0.w;
      a1.x += v1.x; a1.y += v1.y; a1.z += v1.z; a1.w += v1.w;
      a2.x += v2.x; a2.y += v2.y; a2.z += v2.z; a2.w += v2.w;
      a3.x += v3.x; a3.y += v3.y; a3.z += v3.z; a3.w += v3.w;
    }
    for (; e < e1; ++e) {
      int s = stage[e];
      float4 v = ((const float4*)(x + (size_t)s * DIM))[part];
      a0.x += v.x; a0.y += v.y; a0.z += v.z; a0.w += v.w;
    }
    float4 acc;
    acc.x = (a0.x + a1.x) + (a2.x + a3.x);
    acc.y = (a0.y + a1.y) + (a2.y + a3.y);
    acc.z = (a0.z + a1.z) + (a2.z + a3.z);
    acc.w = (a0.w + a1.w) + (a2.w + a3.w);
    ((float4*)(agg + (size_t)node * DIM))[part] = acc;
  }
}

// ---------------- fused1: h1 = ((1+eps)*x + agg) @ W1 + b1 (in-place) -------
__global__ __launch_bounds__(256) void fused1_kernel(
    const float* __restrict__ x, float* __restrict__ h1,
    const float* __restrict__ W1, const float* __restrict__ b1,
    const float* __restrict__ epsp, int N) {
  __shared__ float Ws[DIM * DIM];
  __shared__ float bs[DIM];
  for (int t = threadIdx.x; t < DIM * DIM / 4; t += 256)
    ((float4*)Ws)[t] = ((const float4*)W1)[t];
  if (threadIdx.x < DIM / 4)
    ((float4*)bs)[threadIdx.x] = ((const float4*)b1)[threadIdx.x];
  __syncthreads();
  int i = blockIdx.x * 256 + threadIdx.x;
  if (i >= N) return;
  float onep = 1.0f + epsp[0];
  float h[DIM];
  const float4* xr = (const float4*)(x + (size_t)i * DIM);
  float4* ar = (float4*)(h1 + (size_t)i * DIM);
#pragma unroll
  for (int k4 = 0; k4 < 16; ++k4) {
    float4 a = xr[k4];
    float4 g = ar[k4];
    h[k4 * 4 + 0] = fmaf(onep, a.x, g.x);
    h[k4 * 4 + 1] = fmaf(onep, a.y, g.y);
    h[k4 * 4 + 2] = fmaf(onep, a.z, g.z);
    h[k4 * 4 + 3] = fmaf(onep, a.w, g.w);
  }
#pragma unroll 1
  for (int jt = 0; jt < DIM; jt += 16) {
    float acc[16];
#pragma unroll
    for (int q = 0; q < 4; ++q) {
      float4 b = ((const float4*)&bs[jt])[q];
      acc[q * 4 + 0] = b.x;
      acc[q * 4 + 1] = b.y;
      acc[q * 4 + 2] = b.z;
      acc[q * 4 + 3] = b.w;
    }
#pragma unroll
    for (int k = 0; k < DIM; ++k) {
      float hk = h[k];
      const float4* wr = (const float4*)&Ws[k * DIM + jt];
#pragma unroll
      for (int q = 0; q < 4; ++q) {
        float4 w = wr[q];
        acc[q * 4 + 0] = fmaf(hk, w.x, acc[q * 4 + 0]);
        acc[q * 4 + 1] = fmaf(hk, w.y, acc[q * 4 + 1]);
        acc[q * 4 + 2] = fmaf(hk, w.z, acc[q * 4 + 2]);
        acc[q * 4 + 3] = fmaf(hk, w.w, acc[q * 4 + 3]);
      }
    }
    float4* orow = (float4*)(h1 + (size_t)i * DIM + jt);
#pragma unroll
    for (int q = 0; q < 4; ++q)
      orow[q] = make_float4(acc[q * 4 + 0], acc[q * 4 + 1],
                            acc[q * 4 + 2], acc[q * 4 + 3]);
  }
}

// ---------------- BN stats: per-column sum and sumsq over N rows ------------
__global__ __launch_bounds__(256) void stats_kernel(
    const float* __restrict__ h1, float* __restrict__ sums,
    float* __restrict__ sumsq, int N) {
  int j = threadIdx.x & 63;
  int rsub = threadIdx.x >> 6;  // 0..3
  float s = 0.0f, q = 0.0f;
  for (int r = blockIdx.x * 4 + rsub; r < N; r += gridDim.x * 4) {
    float v = h1[(size_t)r * DIM + j];
    s += v;
    q = fmaf(v, v, q);
  }
  __shared__ float ls[256];
  __shared__ float lq[256];
  ls[threadIdx.x] = s;
  lq[threadIdx.x] = q;
  __syncthreads();
  if (threadIdx.x < 64) {
    s = ls[j] + ls[j + 64] + ls[j + 128] + ls[j + 192];
    q = lq[j] + lq[j + 64] + lq[j + 128] + lq[j + 192];
    atomicAdd(&sums[j], s);
    atomicAdd(&sumsq[j], q);
  }
}

// ---------------- fused2: out = relu(bn(h1)) @ W2 + b2 ----------------------
__global__ __launch_bounds__(256) void fused2_kernel(
    const float* __restrict__ h1, float* __restrict__ out,
    const float* __restrict__ W2, const float* __restrict__ b2,
    const float* __restrict__ gamma, const float* __restrict__ beta,
    const float* __restrict__ sums, const float* __restrict__ sumsq, int N) {
  __shared__ float Ws[DIM * DIM];
  __shared__ float bs[DIM];
  __shared__ float sc_s[DIM];
  __shared__ float sh_s[DIM];
  for (int t = threadIdx.x; t < DIM * DIM / 4; t += 256)
    ((float4*)Ws)[t] = ((const float4*)W2)[t];
  if (threadIdx.x < DIM / 4)
    ((float4*)bs)[threadIdx.x] = ((const float4*)b2)[threadIdx.x];
  if (threadIdx.x >= 64 && threadIdx.x < 128) {
    int j = threadIdx.x - 64;
    float invN = 1.0f / (float)N;
    float m = sums[j] * invN;
    float v = fmaf(-m, m, sumsq[j] * invN);
    float sc = gamma[j] * rsqrtf(v + 1e-5f);
    sc_s[j] = sc;
    sh_s[j] = fmaf(-m, sc, beta[j]);
  }
  __syncthreads();
  int i = blockIdx.x * 256 + threadIdx.x;
  if (i >= N) return;
  float h[DIM];
  const float4* hr = (const float4*)(h1 + (size_t)i * DIM);
#pragma unroll
  for (int k4 = 0; k4 < 16; ++k4) {
    float4 a = hr[k4];
    float4 sc = ((const float4*)sc_s)[k4];
    float4 sh = ((const float4*)sh_s)[k4];
    h[k4 * 4 + 0] = fmaxf(fmaf(a.x, sc.x, sh.x), 0.0f);
    h[k4 * 4 + 1] = fmaxf(fmaf(a.y, sc.y, sh.y), 0.0f);
    h[k4 * 4 + 2] = fmaxf(fmaf(a.z, sc.z, sh.z), 0.0f);
    h[k4 * 4 + 3] = fmaxf(fmaf(a.w, sc.w, sh.w), 0.0f);
  }
#pragma unroll 1
  for (int jt = 0; jt < DIM; jt += 16) {
    float acc[16];
#pragma unroll
    for (int q = 0; q < 4; ++q) {
      float4 b = ((const float4*)&bs[jt])[q];
      acc[q * 4 + 0] = b.x;
      acc[q * 4 + 1] = b.y;
      acc[q * 4 + 2] = b.z;
      acc[q * 4 + 3] = b.w;
    }
#pragma unroll
    for (int k = 0; k < DIM; ++k) {
      float hk = h[k];
      const float4* wr = (const float4*)&Ws[k * DIM + jt];
#pragma unroll
      for (int q = 0; q < 4; ++q) {
        float4 w = wr[q];
        acc[q * 4 + 0] = fmaf(hk, w.x, acc[q * 4 + 0]);
        acc[q * 4 + 1] = fmaf(hk, w.y, acc[q * 4 + 1]);
        acc[q * 4 + 2] = fmaf(hk, w.z, acc[q * 4 + 2]);
        acc[q * 4 + 3] = fmaf(hk, w.w, acc[q * 4 + 3]);
      }
    }
    float4* orow = (float4*)(out + (size_t)i * DIM + jt);
#pragma unroll
    for (int q = 0; q < 4; ++q)
      orow[q] = make_float4(acc[q * 4 + 0], acc[q * 4 + 1],
                            acc[q * 4 + 2], acc[q * 4 + 3]);
  }
}

extern "C" void kernel_launch(void* const* d_in, const int* in_sizes, int n_in,
                              void* d_out, int out_size, void* d_ws, size_t ws_size,
                              hipStream_t stream) {
  (void)in_sizes; (void)n_in; (void)out_size; (void)ws_size;
  const float* x     = (const float*)d_in[0];
  const int*   ei    = (const int*)d_in[1];
  const float* eps   = (const float*)d_in[2];
  const float* W1    = (const float*)d_in[3];
  const float* b1    = (const float*)d_in[4];
  const float* gamma = (const float*)d_in[5];
  const float* beta  = (const float*)d_in[6];
  const float* W2    = (const float*)d_in[7];
  const float* b2    = (const float*)d_in[8];
  float* outp = (float*)d_out;

  const int N = NNODES;

  // workspace (~25.8 MB): agg reused as h1
  float* agg     = (float*)d_ws;                 // N*64 f32
  float* sums    = agg + (size_t)N * DIM;        // 64 f32 (zeroed)
  float* sumsq   = sums + DIM;                   // 64 f32 (zeroed)
  int*   gcursor = (int*)(sumsq + DIM);          // NB int
  // bpart (NB*CAP ints = 12.8 MB) lives in d_out: dead before fused2
  // fully overwrites d_out. No overlap hazard with agg.
  int*   bpart   = (int*)d_out;

  hipMemsetAsync(sums, 0, 2 * DIM * sizeof(float), stream);

  init_kernel       <<<1, 1024, 0, stream>>>(gcursor);
  partition_kernel  <<<NPB, 1024, 0, stream>>>(ei, gcursor, bpart);
  sort_gather_kernel<<<NB, 512, 0, stream>>>(bpart, gcursor, x, agg);
  fused1_kernel     <<<(N + 255) / 256, 256, 0, stream>>>(x, agg, W1, b1, eps, N);
  stats_kernel      <<<512, 256, 0, stream>>>(agg, sums, sumsq, N);
  fused2_kernel     <<<(N + 255) / 256, 256, 0, stream>>>(agg, outp, W2, b2,
                                                          gamma, beta, sums, sumsq, N);
}

// Round 7
// 254.051 us; speedup vs baseline: 1.0829x; 1.0829x over previous
//
#include <hip/hip_runtime.h>

#define NNODES 100000
#define NEDGES 1600000
#define DIM 64
#define NB 782          // buckets of 128 nodes (dst >> 7); 782*128 = 100096
#define NPB 512         // partition blocks
#define CHUNK 3125      // edges per partition block (NPB * CHUNK == NEDGES)
#define CAP 4064        // padded slots per bucket (mean 2048, sigma 45 -> 44 sigma)

__device__ __forceinline__ unsigned short bf16_rne(float f) {
  unsigned u = __float_as_uint(f);
  u += 0x7FFF + ((u >> 16) & 1);
  return (unsigned short)(u >> 16);
}
__device__ __forceinline__ float bf16_to_f32(unsigned short h) {
  return __uint_as_float(((unsigned)h) << 16);
}

// ---------------- P0: init cursors + zero stats accumulators ----------------
__global__ __launch_bounds__(1024) void init_kernel(
    int* __restrict__ gcursor, float* __restrict__ sums) {
  int t = threadIdx.x;
  if (t < NB) gcursor[t] = t * CAP;
  if (t < 2 * DIM) sums[t] = 0.0f;   // sums[64] + sumsq[64] contiguous
}

// ---------------- P0b: x (f32) -> bf16 table --------------------------------
__global__ __launch_bounds__(256) void convert_kernel(
    const float* __restrict__ x, unsigned short* __restrict__ xb) {
  int i = blockIdx.x * 256 + threadIdx.x;   // N*DIM/4 threads exactly
  float4 v = ((const float4*)x)[i];
  ushort4 o;
  o.x = bf16_rne(v.x); o.y = bf16_rne(v.y);
  o.z = bf16_rne(v.z); o.w = bf16_rne(v.w);
  ((ushort4*)xb)[i] = o;
}

// ---------------- P1: partition edges into padded buckets -------------------
__global__ __launch_bounds__(1024) void partition_kernel(
    const int* __restrict__ ei, int* __restrict__ gcursor,
    int* __restrict__ bpart) {
  __shared__ int lh[NB];
  __shared__ int cur[NB];
  int t = threadIdx.x;
  for (int b = t; b < NB; b += 1024) lh[b] = 0;
  __syncthreads();
  int base = blockIdx.x * CHUNK;
  for (int i = t; i < CHUNK; i += 1024)
    atomicAdd(&lh[ei[NEDGES + base + i] >> 7], 1);
  __syncthreads();
  for (int b = t; b < NB; b += 1024) {
    int c = lh[b];
    cur[b] = c ? atomicAdd(&gcursor[b], c) : 0;   // reserve contiguous run
  }
  __syncthreads();
  for (int i = t; i < CHUNK; i += 1024) {
    int s = ei[base + i];
    int d = ei[NEDGES + base + i];
    int p = atomicAdd(&cur[d >> 7], 1);
    bpart[p] = ((d & 127) << 17) | s;   // src < 2^17, dlow in bits 17..23
  }
}

// ---------------- P2: per-bucket LDS sort + bf16 gather, fused --------------
__global__ __launch_bounds__(512) void sort_gather_kernel(
    const int* __restrict__ bpart, const int* __restrict__ gcursor,
    const unsigned short* __restrict__ xb, float* __restrict__ agg) {
  __shared__ int sd[128];     // per-node degree -> inclusive scan
  __shared__ int cur[128];    // scatter cursors
  __shared__ int stage[CAP];  // sorted src list for this bucket
  int b = blockIdx.x;
  int t = threadIdx.x;
  int pbase = b * CAP;
  int cnt = gcursor[b] - pbase;
  if (t < 128) sd[t] = 0;
  __syncthreads();
  for (int i = t; i < cnt; i += 512)
    atomicAdd(&sd[bpart[pbase + i] >> 17], 1);
  __syncthreads();
  int deg = (t < 128) ? sd[t] : 0;
  for (int off = 1; off < 128; off <<= 1) {   // inclusive scan of degrees
    int a = (t < 128 && t >= off) ? sd[t - off] : 0;
    __syncthreads();
    if (t < 128) sd[t] += a;
    __syncthreads();
  }
  if (t < 128) cur[t] = sd[t] - deg;          // exclusive start
  __syncthreads();
  for (int i = t; i < cnt; i += 512) {
    int v = bpart[pbase + i];
    int p = atomicAdd(&cur[v >> 17], 1);
    stage[p] = v & 0x1FFFF;                   // LDS scatter, cheap
  }
  __syncthreads();
  // gather: 32 nodes concurrently x 16 lanes, 4 passes over 128 nodes
  int part = t & 15;
  int ng = t >> 4;                            // 0..31
#pragma unroll 1
  for (int pass = 0; pass < 4; ++pass) {
    int nl = ng + pass * 32;                  // local node 0..127
    int node = b * 128 + nl;
    if (node >= NNODES) continue;
    int e0 = (nl == 0) ? 0 : sd[nl - 1];
    int e1 = sd[nl];
    float4 a0 = make_float4(0.f, 0.f, 0.f, 0.f);
    float4 a1 = a0, a2 = a0, a3 = a0;
    int e = e0;
    for (; e + 4 <= e1; e += 4) {             // 4 independent 8B loads in flight
      int s0 = stage[e + 0];
      int s1 = stage[e + 1];
      int s2 = stage[e + 2];
      int s3 = stage[e + 3];
      ushort4 u0 = ((const ushort4*)(xb + (size_t)s0 * DIM))[part];
      ushort4 u1 = ((const ushort4*)(xb + (size_t)s1 * DIM))[part];
      ushort4 u2 = ((const ushort4*)(xb + (size_t)s2 * DIM))[part];
      ushort4 u3 = ((const ushort4*)(xb + (size_t)s3 * DIM))[part];
      a0.x += bf16_to_f32(u0.x); a0.y += bf16_to_f32(u0.y);
      a0.z += bf16_to_f32(u0.z); a0.w += bf16_to_f32(u0.w);
      a1.x += bf16_to_f32(u1.x); a1.y += bf16_to_f32(u1.y);
      a1.z += bf16_to_f32(u1.z); a1.w += bf16_to_f32(u1.w);
      a2.x += bf16_to_f32(u2.x); a2.y += bf16_to_f32(u2.y);
      a2.z += bf16_to_f32(u2.z); a2.w += bf16_to_f32(u2.w);
      a3.x += bf16_to_f32(u3.x); a3.y += bf16_to_f32(u3.y);
      a3.z += bf16_to_f32(u3.z); a3.w += bf16_to_f32(u3.w);
    }
    for (; e < e1; ++e) {
      int s = stage[e];
      ushort4 u = ((const ushort4*)(xb + (size_t)s * DIM))[part];
      a0.x += bf16_to_f32(u.x); a0.y += bf16_to_f32(u.y);
      a0.z += bf16_to_f32(u.z); a0.w += bf16_to_f32(u.w);
    }
    float4 acc;
    acc.x = (a0.x + a1.x) + (a2.x + a3.x);
    acc.y = (a0.y + a1.y) + (a2.y + a3.y);
    acc.z = (a0.z + a1.z) + (a2.z + a3.z);
    acc.w = (a0.w + a1.w) + (a2.w + a3.w);
    ((float4*)(agg + (size_t)node * DIM))[part] = acc;
  }
}

// ---------------- fused1: h1 = ((1+eps)*x + agg) @ W1 + b1 (in-place) -------
__global__ __launch_bounds__(256) void fused1_kernel(
    const float* __restrict__ x, float* __restrict__ h1,
    const float* __restrict__ W1, const float* __restrict__ b1,
    const float* __restrict__ epsp, int N) {
  __shared__ float Ws[DIM * DIM];
  __shared__ float bs[DIM];
  for (int t = threadIdx.x; t < DIM * DIM / 4; t += 256)
    ((float4*)Ws)[t] = ((const float4*)W1)[t];
  if (threadIdx.x < DIM / 4)
    ((float4*)bs)[threadIdx.x] = ((const float4*)b1)[threadIdx.x];
  __syncthreads();
  int i = blockIdx.x * 256 + threadIdx.x;
  if (i >= N) return;
  float onep = 1.0f + epsp[0];
  float h[DIM];
  const float4* xr = (const float4*)(x + (size_t)i * DIM);
  float4* ar = (float4*)(h1 + (size_t)i * DIM);
#pragma unroll
  for (int k4 = 0; k4 < 16; ++k4) {
    float4 a = xr[k4];
    float4 g = ar[k4];
    h[k4 * 4 + 0] = fmaf(onep, a.x, g.x);
    h[k4 * 4 + 1] = fmaf(onep, a.y, g.y);
    h[k4 * 4 + 2] = fmaf(onep, a.z, g.z);
    h[k4 * 4 + 3] = fmaf(onep, a.w, g.w);
  }
#pragma unroll 1
  for (int jt = 0; jt < DIM; jt += 16) {
    float acc[16];
#pragma unroll
    for (int q = 0; q < 4; ++q) {
      float4 b = ((const float4*)&bs[jt])[q];
      acc[q * 4 + 0] = b.x;
      acc[q * 4 + 1] = b.y;
      acc[q * 4 + 2] = b.z;
      acc[q * 4 + 3] = b.w;
    }
#pragma unroll
    for (int k = 0; k < DIM; ++k) {
      float hk = h[k];
      const float4* wr = (const float4*)&Ws[k * DIM + jt];
#pragma unroll
      for (int q = 0; q < 4; ++q) {
        float4 w = wr[q];
        acc[q * 4 + 0] = fmaf(hk, w.x, acc[q * 4 + 0]);
        acc[q * 4 + 1] = fmaf(hk, w.y, acc[q * 4 + 1]);
        acc[q * 4 + 2] = fmaf(hk, w.z, acc[q * 4 + 2]);
        acc[q * 4 + 3] = fmaf(hk, w.w, acc[q * 4 + 3]);
      }
    }
    float4* orow = (float4*)(h1 + (size_t)i * DIM + jt);
#pragma unroll
    for (int q = 0; q < 4; ++q)
      orow[q] = make_float4(acc[q * 4 + 0], acc[q * 4 + 1],
                            acc[q * 4 + 2], acc[q * 4 + 3]);
  }
}

// ---------------- BN stats: per-column sum and sumsq over N rows ------------
__global__ __launch_bounds__(256) void stats_kernel(
    const float* __restrict__ h1, float* __restrict__ sums,
    float* __restrict__ sumsq, int N) {
  int j = threadIdx.x & 63;
  int rsub = threadIdx.x >> 6;  // 0..3
  float s = 0.0f, q = 0.0f;
  for (int r = blockIdx.x * 4 + rsub; r < N; r += gridDim.x * 4) {
    float v = h1[(size_t)r * DIM + j];
    s += v;
    q = fmaf(v, v, q);
  }
  __shared__ float ls[256];
  __shared__ float lq[256];
  ls[threadIdx.x] = s;
  lq[threadIdx.x] = q;
  __syncthreads();
  if (threadIdx.x < 64) {
    s = ls[j] + ls[j + 64] + ls[j + 128] + ls[j + 192];
    q = lq[j] + lq[j + 64] + lq[j + 128] + lq[j + 192];
    atomicAdd(&sums[j], s);
    atomicAdd(&sumsq[j], q);
  }
}

// ---------------- fused2: out = relu(bn(h1)) @ W2 + b2 ----------------------
__global__ __launch_bounds__(256) void fused2_kernel(
    const float* __restrict__ h1, float* __restrict__ out,
    const float* __restrict__ W2, const float* __restrict__ b2,
    const float* __restrict__ gamma, const float* __restrict__ beta,
    const float* __restrict__ sums, const float* __restrict__ sumsq, int N) {
  __shared__ float Ws[DIM * DIM];
  __shared__ float bs[DIM];
  __shared__ float sc_s[DIM];
  __shared__ float sh_s[DIM];
  for (int t = threadIdx.x; t < DIM * DIM / 4; t += 256)
    ((float4*)Ws)[t] = ((const float4*)W2)[t];
  if (threadIdx.x < DIM / 4)
    ((float4*)bs)[threadIdx.x] = ((const float4*)b2)[threadIdx.x];
  if (threadIdx.x >= 64 && threadIdx.x < 128) {
    int j = threadIdx.x - 64;
    float invN = 1.0f / (float)N;
    float m = sums[j] * invN;
    float v = fmaf(-m, m, sumsq[j] * invN);
    float sc = gamma[j] * rsqrtf(v + 1e-5f);
    sc_s[j] = sc;
    sh_s[j] = fmaf(-m, sc, beta[j]);
  }
  __syncthreads();
  int i = blockIdx.x * 256 + threadIdx.x;
  if (i >= N) return;
  float h[DIM];
  const float4* hr = (const float4*)(h1 + (size_t)i * DIM);
#pragma unroll
  for (int k4 = 0; k4 < 16; ++k4) {
    float4 a = hr[k4];
    float4 sc = ((const float4*)sc_s)[k4];
    float4 sh = ((const float4*)sh_s)[k4];
    h[k4 * 4 + 0] = fmaxf(fmaf(a.x, sc.x, sh.x), 0.0f);
    h[k4 * 4 + 1] = fmaxf(fmaf(a.y, sc.y, sh.y), 0.0f);
    h[k4 * 4 + 2] = fmaxf(fmaf(a.z, sc.z, sh.z), 0.0f);
    h[k4 * 4 + 3] = fmaxf(fmaf(a.w, sc.w, sh.w), 0.0f);
  }
#pragma unroll 1
  for (int jt = 0; jt < DIM; jt += 16) {
    float acc[16];
#pragma unroll
    for (int q = 0; q < 4; ++q) {
      float4 b = ((const float4*)&bs[jt])[q];
      acc[q * 4 + 0] = b.x;
      acc[q * 4 + 1] = b.y;
      acc[q * 4 + 2] = b.z;
      acc[q * 4 + 3] = b.w;
    }
#pragma unroll
    for (int k = 0; k < DIM; ++k) {
      float hk = h[k];
      const float4* wr = (const float4*)&Ws[k * DIM + jt];
#pragma unroll
      for (int q = 0; q < 4; ++q) {
        float4 w = wr[q];
        acc[q * 4 + 0] = fmaf(hk, w.x, acc[q * 4 + 0]);
        acc[q * 4 + 1] = fmaf(hk, w.y, acc[q * 4 + 1]);
        acc[q * 4 + 2] = fmaf(hk, w.z, acc[q * 4 + 2]);
        acc[q * 4 + 3] = fmaf(hk, w.w, acc[q * 4 + 3]);
      }
    }
    float4* orow = (float4*)(out + (size_t)i * DIM + jt);
#pragma unroll
    for (int q = 0; q < 4; ++q)
      orow[q] = make_float4(acc[q * 4 + 0], acc[q * 4 + 1],
                            acc[q * 4 + 2], acc[q * 4 + 3]);
  }
}

extern "C" void kernel_launch(void* const* d_in, const int* in_sizes, int n_in,
                              void* d_out, int out_size, void* d_ws, size_t ws_size,
                              hipStream_t stream) {
  (void)in_sizes; (void)n_in; (void)out_size; (void)ws_size;
  const float* x     = (const float*)d_in[0];
  const int*   ei    = (const int*)d_in[1];
  const float* eps   = (const float*)d_in[2];
  const float* W1    = (const float*)d_in[3];
  const float* b1    = (const float*)d_in[4];
  const float* gamma = (const float*)d_in[5];
  const float* beta  = (const float*)d_in[6];
  const float* W2    = (const float*)d_in[7];
  const float* b2    = (const float*)d_in[8];
  float* outp = (float*)d_out;

  const int N = NNODES;

  // workspace (~25.6 MB): agg reused as h1
  float* agg     = (float*)d_ws;                 // N*64 f32
  float* sums    = agg + (size_t)N * DIM;        // 64 f32 (zeroed in init)
  float* sumsq   = sums + DIM;                   // 64 f32 (zeroed in init)
  int*   gcursor = (int*)(sumsq + DIM);          // NB int
  // d_out scratch (dead before fused2 overwrites it):
  //   bpart:  NB*CAP ints   = 12.71 MB
  //   xb:     N*DIM bf16    = 12.80 MB   (total 25.51 <= 25.6 MB of d_out)
  int*            bpart = (int*)d_out;
  unsigned short* xb    = (unsigned short*)d_out + (size_t)NB * CAP * 2;

  init_kernel       <<<1, 1024, 0, stream>>>(gcursor, sums);
  convert_kernel    <<<N * DIM / 4 / 256, 256, 0, stream>>>(x, xb);
  partition_kernel  <<<NPB, 1024, 0, stream>>>(ei, gcursor, bpart);
  sort_gather_kernel<<<NB, 512, 0, stream>>>(bpart, gcursor, xb, agg);
  fused1_kernel     <<<(N + 255) / 256, 256, 0, stream>>>(x, agg, W1, b1, eps, N);
  stats_kernel      <<<512, 256, 0, stream>>>(agg, sums, sumsq, N);
  fused2_kernel     <<<(N + 255) / 256, 256, 0, stream>>>(agg, outp, W2, b2,
                                                          gamma, beta, sums, sumsq, N);
}

// Round 8
// 206.274 us; speedup vs baseline: 1.3337x; 1.2316x over previous
//
#include <hip/hip_runtime.h>

#define NNODES 100000
#define NEDGES 1600000
#define DIM 64
#define NB 782          // buckets of 128 nodes (dst >> 7); 782*128 = 100096
#define NPB 512         // partition blocks
#define CHUNK 3125      // edges per partition block (NPB * CHUNK == NEDGES)
#define CAP 4064        // padded slots per bucket (mean 2048, sigma 45 -> 44 sigma)
#define NTILES 6250     // 100000 / 16 row-tiles for MFMA GEMMs

typedef __attribute__((ext_vector_type(4))) float f32x4;
typedef __attribute__((ext_vector_type(8))) short s16x8;   // 8 bf16 in 4 VGPRs

__device__ __forceinline__ unsigned short bf16_rne(float f) {
  unsigned u = __float_as_uint(f);
  u += 0x7FFF + ((u >> 16) & 1);
  return (unsigned short)(u >> 16);
}
__device__ __forceinline__ float bf16_to_f32(unsigned short h) {
  return __uint_as_float(((unsigned)h) << 16);
}

// ---------------- P0: init cursors + zero stats accumulators ----------------
__global__ __launch_bounds__(1024) void init_kernel(
    int* __restrict__ gcursor, float* __restrict__ sums) {
  int t = threadIdx.x;
  if (t < NB) gcursor[t] = t * CAP;
  if (t < 2 * DIM) sums[t] = 0.0f;   // sums[64] + sumsq[64] contiguous
}

// ---------------- P0b: x (f32) -> bf16 table --------------------------------
__global__ __launch_bounds__(256) void convert_kernel(
    const float* __restrict__ x, unsigned short* __restrict__ xb) {
  int i = blockIdx.x * 256 + threadIdx.x;   // N*DIM/4 threads exactly
  float4 v = ((const float4*)x)[i];
  ushort4 o;
  o.x = bf16_rne(v.x); o.y = bf16_rne(v.y);
  o.z = bf16_rne(v.z); o.w = bf16_rne(v.w);
  ((ushort4*)xb)[i] = o;
}

// ---------------- P0c: pack W1/W2 into MFMA B-fragment layout ---------------
// B-frag for mfma_f32_16x16x32_bf16: lane L holds B[k = 8*(L>>4)+j][n = L&15],
// j=0..7, for each (kk,nt) sub-tile. Wp[f=kk*4+nt][lane][j].
__global__ __launch_bounds__(128) void pack_kernel(
    const float* __restrict__ W1, const float* __restrict__ W2,
    unsigned short* __restrict__ Wp1, unsigned short* __restrict__ Wp2) {
  int lane = threadIdx.x & 63;
  const float* W = (threadIdx.x >= 64) ? W2 : W1;
  unsigned short* Wp = (threadIdx.x >= 64) ? Wp2 : Wp1;
  int q = lane >> 4, n16 = lane & 15;
#pragma unroll
  for (int f = 0; f < 8; ++f) {
    int kk = f >> 2, nt = f & 3;
#pragma unroll
    for (int j = 0; j < 8; ++j) {
      int k = kk * 32 + q * 8 + j;
      int n = nt * 16 + n16;
      Wp[f * 512 + lane * 8 + j] = bf16_rne(W[k * DIM + n]);
    }
  }
}

// ---------------- P1: partition edges into padded buckets -------------------
__global__ __launch_bounds__(1024) void partition_kernel(
    const int* __restrict__ ei, int* __restrict__ gcursor,
    int* __restrict__ bpart) {
  __shared__ int lh[NB];
  __shared__ int cur[NB];
  int t = threadIdx.x;
  for (int b = t; b < NB; b += 1024) lh[b] = 0;
  __syncthreads();
  int base = blockIdx.x * CHUNK;
  for (int i = t; i < CHUNK; i += 1024)
    atomicAdd(&lh[ei[NEDGES + base + i] >> 7], 1);
  __syncthreads();
  for (int b = t; b < NB; b += 1024) {
    int c = lh[b];
    cur[b] = c ? atomicAdd(&gcursor[b], c) : 0;   // reserve contiguous run
  }
  __syncthreads();
  for (int i = t; i < CHUNK; i += 1024) {
    int s = ei[base + i];
    int d = ei[NEDGES + base + i];
    int p = atomicAdd(&cur[d >> 7], 1);
    bpart[p] = ((d & 127) << 17) | s;   // src < 2^17, dlow in bits 17..23
  }
}

// ---------------- P2: per-bucket LDS sort + bf16 gather, fused --------------
__global__ __launch_bounds__(512) void sort_gather_kernel(
    const int* __restrict__ bpart, const int* __restrict__ gcursor,
    const unsigned short* __restrict__ xb, float* __restrict__ agg) {
  __shared__ int sd[128];     // per-node degree -> inclusive scan
  __shared__ int cur[128];    // scatter cursors
  __shared__ int stage[CAP];  // sorted src list for this bucket
  int b = blockIdx.x;
  int t = threadIdx.x;
  int pbase = b * CAP;
  int cnt = gcursor[b] - pbase;
  if (t < 128) sd[t] = 0;
  __syncthreads();
  for (int i = t; i < cnt; i += 512)
    atomicAdd(&sd[bpart[pbase + i] >> 17], 1);
  __syncthreads();
  int deg = (t < 128) ? sd[t] : 0;
  for (int off = 1; off < 128; off <<= 1) {   // inclusive scan of degrees
    int a = (t < 128 && t >= off) ? sd[t - off] : 0;
    __syncthreads();
    if (t < 128) sd[t] += a;
    __syncthreads();
  }
  if (t < 128) cur[t] = sd[t] - deg;          // exclusive start
  __syncthreads();
  for (int i = t; i < cnt; i += 512) {
    int v = bpart[pbase + i];
    int p = atomicAdd(&cur[v >> 17], 1);
    stage[p] = v & 0x1FFFF;                   // LDS scatter, cheap
  }
  __syncthreads();
  // gather: 32 nodes concurrently x 16 lanes, 4 passes over 128 nodes
  int part = t & 15;
  int ng = t >> 4;                            // 0..31
#pragma unroll 1
  for (int pass = 0; pass < 4; ++pass) {
    int nl = ng + pass * 32;                  // local node 0..127
    int node = b * 128 + nl;
    if (node >= NNODES) continue;
    int e0 = (nl == 0) ? 0 : sd[nl - 1];
    int e1 = sd[nl];
    float4 a0 = make_float4(0.f, 0.f, 0.f, 0.f);
    float4 a1 = a0, a2 = a0, a3 = a0;
    int e = e0;
    for (; e + 4 <= e1; e += 4) {             // 4 independent 8B loads in flight
      int s0 = stage[e + 0];
      int s1 = stage[e + 1];
      int s2 = stage[e + 2];
      int s3 = stage[e + 3];
      ushort4 u0 = ((const ushort4*)(xb + (size_t)s0 * DIM))[part];
      ushort4 u1 = ((const ushort4*)(xb + (size_t)s1 * DIM))[part];
      ushort4 u2 = ((const ushort4*)(xb + (size_t)s2 * DIM))[part];
      ushort4 u3 = ((const ushort4*)(xb + (size_t)s3 * DIM))[part];
      a0.x += bf16_to_f32(u0.x); a0.y += bf16_to_f32(u0.y);
      a0.z += bf16_to_f32(u0.z); a0.w += bf16_to_f32(u0.w);
      a1.x += bf16_to_f32(u1.x); a1.y += bf16_to_f32(u1.y);
      a1.z += bf16_to_f32(u1.z); a1.w += bf16_to_f32(u1.w);
      a2.x += bf16_to_f32(u2.x); a2.y += bf16_to_f32(u2.y);
      a2.z += bf16_to_f32(u2.z); a2.w += bf16_to_f32(u2.w);
      a3.x += bf16_to_f32(u3.x); a3.y += bf16_to_f32(u3.y);
      a3.z += bf16_to_f32(u3.z); a3.w += bf16_to_f32(u3.w);
    }
    for (; e < e1; ++e) {
      int s = stage[e];
      ushort4 u = ((const ushort4*)(xb + (size_t)s * DIM))[part];
      a0.x += bf16_to_f32(u.x); a0.y += bf16_to_f32(u.y);
      a0.z += bf16_to_f32(u.z); a0.w += bf16_to_f32(u.w);
    }
    float4 acc;
    acc.x = (a0.x + a1.x) + (a2.x + a3.x);
    acc.y = (a0.y + a1.y) + (a2.y + a3.y);
    acc.z = (a0.z + a1.z) + (a2.z + a3.z);
    acc.w = (a0.w + a1.w) + (a2.w + a3.w);
    ((float4*)(agg + (size_t)node * DIM))[part] = acc;
  }
}

// ---------------- fused1 (MFMA): h1 = ((1+eps)*x + agg) @ W1 + b1 -----------
// wave = 16-row tile; A-frag built in-register; W1 pre-packed B-frags.
__global__ __launch_bounds__(256) void fused1_kernel(
    const float* __restrict__ x, float* __restrict__ h1,
    const unsigned short* __restrict__ Wp, const float* __restrict__ b1,
    const float* __restrict__ epsp) {
  int wave = threadIdx.x >> 6;
  int lane = threadIdx.x & 63;
  int tile = blockIdx.x * 4 + wave;
  if (tile >= NTILES) return;
  int q = lane >> 4;      // quad 0..3
  int r16 = lane & 15;
  float onep = 1.0f + epsp[0];
  s16x8 bf[8];
#pragma unroll
  for (int f = 0; f < 8; ++f)
    bf[f] = ((const s16x8*)Wp)[f * 64 + lane];
  int arow = tile * 16 + r16;
  const float* xr = x + (size_t)arow * DIM + q * 8;
  const float* gr = h1 + (size_t)arow * DIM + q * 8;   // h1 aliases agg
  f32x4 acc[4] = {{0.f,0.f,0.f,0.f},{0.f,0.f,0.f,0.f},
                  {0.f,0.f,0.f,0.f},{0.f,0.f,0.f,0.f}};
#pragma unroll
  for (int kk = 0; kk < 2; ++kk) {
    float4 xv0 = *(const float4*)(xr + kk * 32);
    float4 xv1 = *(const float4*)(xr + kk * 32 + 4);
    float4 gv0 = *(const float4*)(gr + kk * 32);
    float4 gv1 = *(const float4*)(gr + kk * 32 + 4);
    s16x8 a;
    a[0] = (short)bf16_rne(fmaf(onep, xv0.x, gv0.x));
    a[1] = (short)bf16_rne(fmaf(onep, xv0.y, gv0.y));
    a[2] = (short)bf16_rne(fmaf(onep, xv0.z, gv0.z));
    a[3] = (short)bf16_rne(fmaf(onep, xv0.w, gv0.w));
    a[4] = (short)bf16_rne(fmaf(onep, xv1.x, gv1.x));
    a[5] = (short)bf16_rne(fmaf(onep, xv1.y, gv1.y));
    a[6] = (short)bf16_rne(fmaf(onep, xv1.z, gv1.z));
    a[7] = (short)bf16_rne(fmaf(onep, xv1.w, gv1.w));
#pragma unroll
    for (int nt = 0; nt < 4; ++nt)
      acc[nt] = __builtin_amdgcn_mfma_f32_16x16x32_bf16(
          a, bf[kk * 4 + nt], acc[nt], 0, 0, 0);
  }
  int orow = tile * 16 + q * 4;
#pragma unroll
  for (int nt = 0; nt < 4; ++nt) {
    int col = nt * 16 + r16;
    float bb = b1[col];
#pragma unroll
    for (int r = 0; r < 4; ++r)
      h1[(size_t)(orow + r) * DIM + col] = acc[nt][r] + bb;
  }
}

// ---------------- BN stats: per-column sum and sumsq over N rows ------------
__global__ __launch_bounds__(256) void stats_kernel(
    const float* __restrict__ h1, float* __restrict__ sums,
    float* __restrict__ sumsq, int N) {
  int j = threadIdx.x & 63;
  int rsub = threadIdx.x >> 6;  // 0..3
  float s = 0.0f, q = 0.0f;
  for (int r = blockIdx.x * 4 + rsub; r < N; r += gridDim.x * 4) {
    float v = h1[(size_t)r * DIM + j];
    s += v;
    q = fmaf(v, v, q);
  }
  __shared__ float ls[256];
  __shared__ float lq[256];
  ls[threadIdx.x] = s;
  lq[threadIdx.x] = q;
  __syncthreads();
  if (threadIdx.x < 64) {
    s = ls[j] + ls[j + 64] + ls[j + 128] + ls[j + 192];
    q = lq[j] + lq[j + 64] + lq[j + 128] + lq[j + 192];
    atomicAdd(&sums[j], s);
    atomicAdd(&sumsq[j], q);
  }
}

// ---------------- fused2 (MFMA): out = relu(bn(h1)) @ W2 + b2 ---------------
__global__ __launch_bounds__(256) void fused2_kernel(
    const float* __restrict__ h1, float* __restrict__ out,
    const unsigned short* __restrict__ Wp, const float* __restrict__ b2,
    const float* __restrict__ gamma, const float* __restrict__ beta,
    const float* __restrict__ sums, const float* __restrict__ sumsq) {
  __shared__ float sc_s[DIM];
  __shared__ float sh_s[DIM];
  int t = threadIdx.x;
  if (t < DIM) {
    float invN = 1.0f / (float)NNODES;
    float m = sums[t] * invN;
    float v = fmaf(-m, m, sumsq[t] * invN);
    float sc = gamma[t] * rsqrtf(v + 1e-5f);
    sc_s[t] = sc;
    sh_s[t] = fmaf(-m, sc, beta[t]);
  }
  __syncthreads();
  int wave = t >> 6;
  int lane = t & 63;
  int tile = blockIdx.x * 4 + wave;
  if (tile >= NTILES) return;
  int q = lane >> 4;
  int r16 = lane & 15;
  s16x8 bf[8];
#pragma unroll
  for (int f = 0; f < 8; ++f)
    bf[f] = ((const s16x8*)Wp)[f * 64 + lane];
  int arow = tile * 16 + r16;
  const float* hr = h1 + (size_t)arow * DIM + q * 8;
  f32x4 acc[4] = {{0.f,0.f,0.f,0.f},{0.f,0.f,0.f,0.f},
                  {0.f,0.f,0.f,0.f},{0.f,0.f,0.f,0.f}};
#pragma unroll
  for (int kk = 0; kk < 2; ++kk) {
    int kbase = kk * 32 + q * 8;
    float4 hv0 = *(const float4*)(hr + kk * 32);
    float4 hv1 = *(const float4*)(hr + kk * 32 + 4);
    float4 sc0 = *(const float4*)(sc_s + kbase);
    float4 sc1 = *(const float4*)(sc_s + kbase + 4);
    float4 sh0 = *(const float4*)(sh_s + kbase);
    float4 sh1 = *(const float4*)(sh_s + kbase + 4);
    s16x8 a;
    a[0] = (short)bf16_rne(fmaxf(fmaf(hv0.x, sc0.x, sh0.x), 0.f));
    a[1] = (short)bf16_rne(fmaxf(fmaf(hv0.y, sc0.y, sh0.y), 0.f));
    a[2] = (short)bf16_rne(fmaxf(fmaf(hv0.z, sc0.z, sh0.z), 0.f));
    a[3] = (short)bf16_rne(fmaxf(fmaf(hv0.w, sc0.w, sh0.w), 0.f));
    a[4] = (short)bf16_rne(fmaxf(fmaf(hv1.x, sc1.x, sh1.x), 0.f));
    a[5] = (short)bf16_rne(fmaxf(fmaf(hv1.y, sc1.y, sh1.y), 0.f));
    a[6] = (short)bf16_rne(fmaxf(fmaf(hv1.z, sc1.z, sh1.z), 0.f));
    a[7] = (short)bf16_rne(fmaxf(fmaf(hv1.w, sc1.w, sh1.w), 0.f));
#pragma unroll
    for (int nt = 0; nt < 4; ++nt)
      acc[nt] = __builtin_amdgcn_mfma_f32_16x16x32_bf16(
          a, bf[kk * 4 + nt], acc[nt], 0, 0, 0);
  }
  int orow = tile * 16 + q * 4;
#pragma unroll
  for (int nt = 0; nt < 4; ++nt) {
    int col = nt * 16 + r16;
    float bb = b2[col];
#pragma unroll
    for (int r = 0; r < 4; ++r)
      out[(size_t)(orow + r) * DIM + col] = acc[nt][r] + bb;
  }
}

extern "C" void kernel_launch(void* const* d_in, const int* in_sizes, int n_in,
                              void* d_out, int out_size, void* d_ws, size_t ws_size,
                              hipStream_t stream) {
  (void)in_sizes; (void)n_in; (void)out_size; (void)ws_size;
  const float* x     = (const float*)d_in[0];
  const int*   ei    = (const int*)d_in[1];
  const float* eps   = (const float*)d_in[2];
  const float* W1    = (const float*)d_in[3];
  const float* b1    = (const float*)d_in[4];
  const float* gamma = (const float*)d_in[5];
  const float* beta  = (const float*)d_in[6];
  const float* W2    = (const float*)d_in[7];
  const float* b2    = (const float*)d_in[8];
  float* outp = (float*)d_out;

  const int N = NNODES;

  // workspace (~25.7 MB): agg reused as h1
  float* agg     = (float*)d_ws;                 // N*64 f32
  float* sums    = agg + (size_t)N * DIM;        // 64 f32 (zeroed in init)
  float* sumsq   = sums + DIM;                   // 64 f32 (zeroed in init)
  int*   gcursor = (int*)(sumsq + DIM);          // NB int
  unsigned short* Wp1 = (unsigned short*)(gcursor + ((NB + 1) & ~1)); // 4096 bf16
  unsigned short* Wp2 = Wp1 + 4096;                                   // 4096 bf16
  // d_out scratch (dead before fused2 overwrites it):
  //   bpart:  NB*CAP ints   = 12.71 MB
  //   xb:     N*DIM bf16    = 12.80 MB   (total 25.51 <= 25.6 MB of d_out)
  int*            bpart = (int*)d_out;
  unsigned short* xb    = (unsigned short*)d_out + (size_t)NB * CAP * 2;

  init_kernel       <<<1, 1024, 0, stream>>>(gcursor, sums);
  convert_kernel    <<<N * DIM / 4 / 256, 256, 0, stream>>>(x, xb);
  pack_kernel       <<<1, 128, 0, stream>>>(W1, W2, Wp1, Wp2);
  partition_kernel  <<<NPB, 1024, 0, stream>>>(ei, gcursor, bpart);
  sort_gather_kernel<<<NB, 512, 0, stream>>>(bpart, gcursor, xb, agg);
  fused1_kernel     <<<(NTILES + 3) / 4, 256, 0, stream>>>(x, agg, Wp1, b1, eps);
  stats_kernel      <<<512, 256, 0, stream>>>(agg, sums, sumsq, N);
  fused2_kernel     <<<(NTILES + 3) / 4, 256, 0, stream>>>(agg, outp, Wp2, b2,
                                                           gamma, beta, sums, sumsq);
}

// Round 9
// 189.601 us; speedup vs baseline: 1.4510x; 1.0879x over previous
//
#include <hip/hip_runtime.h>

#define NNODES 100000
#define NEDGES 1600000
#define DIM 64
#define NB 782          // buckets of 128 nodes (dst >> 7); 782*128 = 100096
#define NPB 256         // partition blocks
#define CHUNK 6250      // edges per partition block (NPB * CHUNK == NEDGES)
#define CAP 3968        // padded slots per bucket (mean 2048, sigma 45 -> 42 sigma)
#define HP 68           // hbuf pitch (64 + 4 pad: phase-C b128 LDS reads 2-way only)
#define NTILES 6250     // 100000 / 16 row-tiles

typedef __attribute__((ext_vector_type(4))) float f32x4;
typedef __attribute__((ext_vector_type(8))) short s16x8;   // 8 bf16 in 4 VGPRs

__device__ __forceinline__ unsigned short bf16_rne(float f) {
  unsigned u = __float_as_uint(f);
  u += 0x7FFF + ((u >> 16) & 1);
  return (unsigned short)(u >> 16);
}
__device__ __forceinline__ float bf16_to_f32(unsigned short h) {
  return __uint_as_float(((unsigned)h) << 16);
}

// ---------------- P0: init cursors, zero stats, pack W1/W2 B-frags ----------
// B-frag for mfma_f32_16x16x32_bf16: lane L holds B[k=8*(L>>4)+j][n=L&15].
__global__ __launch_bounds__(1024) void initpack_kernel(
    int* __restrict__ gcursor, float* __restrict__ sums,
    const float* __restrict__ W1, const float* __restrict__ W2,
    unsigned short* __restrict__ Wp1, unsigned short* __restrict__ Wp2) {
  int t = threadIdx.x;
  if (t < NB) gcursor[t] = t * CAP;
  if (t < 2 * DIM) sums[t] = 0.0f;   // sums[64] + sumsq[64] contiguous
  if (t < 128) {
    int lane = t & 63;
    const float* W = (t >= 64) ? W2 : W1;
    unsigned short* Wp = (t >= 64) ? Wp2 : Wp1;
    int q = lane >> 4, n16 = lane & 15;
#pragma unroll
    for (int f = 0; f < 8; ++f) {
      int kk = f >> 2, nt = f & 3;
#pragma unroll
      for (int j = 0; j < 8; ++j) {
        int k = kk * 32 + q * 8 + j;
        int n = nt * 16 + n16;
        Wp[f * 512 + lane * 8 + j] = bf16_rne(W[k * DIM + n]);
      }
    }
  }
}

// ---------------- P0b: x (f32) -> bf16 table --------------------------------
__global__ __launch_bounds__(256) void convert_kernel(
    const float* __restrict__ x, unsigned short* __restrict__ xb) {
  int i = blockIdx.x * 256 + threadIdx.x;   // N*DIM/4 threads exactly
  float4 v = ((const float4*)x)[i];
  ushort4 o;
  o.x = bf16_rne(v.x); o.y = bf16_rne(v.y);
  o.z = bf16_rne(v.z); o.w = bf16_rne(v.w);
  ((ushort4*)xb)[i] = o;
}

// ---------------- P1: partition edges into padded buckets -------------------
__global__ __launch_bounds__(1024) void partition_kernel(
    const int* __restrict__ ei, int* __restrict__ gcursor,
    int* __restrict__ bpart) {
  __shared__ int lh[NB];
  __shared__ int cur[NB];
  int t = threadIdx.x;
  for (int b = t; b < NB; b += 1024) lh[b] = 0;
  __syncthreads();
  int base = blockIdx.x * CHUNK;
  for (int i = t; i < CHUNK; i += 1024)
    atomicAdd(&lh[ei[NEDGES + base + i] >> 7], 1);
  __syncthreads();
  for (int b = t; b < NB; b += 1024) {
    int c = lh[b];
    cur[b] = c ? atomicAdd(&gcursor[b], c) : 0;   // reserve contiguous run
  }
  __syncthreads();
  for (int i = t; i < CHUNK; i += 1024) {
    int s = ei[base + i];
    int d = ei[NEDGES + base + i];
    int p = atomicAdd(&cur[d >> 7], 1);
    bpart[p] = ((d & 127) << 17) | s;   // src < 2^17, dlow in bits 17..23
  }
}

// ---------------- P2 MEGA: sort + gather + GEMM1 + BN-stats partials --------
// block = one bucket of 128 nodes (8 MFMA row-tiles), 512 threads (8 waves).
__global__ __launch_bounds__(512) void mega_kernel(
    const int* __restrict__ bpart, const int* __restrict__ gcursor,
    const unsigned short* __restrict__ xb, float* __restrict__ h1,
    const unsigned short* __restrict__ Wp, const float* __restrict__ b1,
    const float* __restrict__ epsp,
    float* __restrict__ sums, float* __restrict__ sumsq) {
  __shared__ int sd[128];        // per-node degree -> inclusive scan
  __shared__ int cur[128];       // scatter cursors
  __shared__ int stage[CAP];     // sorted src list for this bucket
  __shared__ float hbuf[128 * HP];  // gathered agg rows (padded pitch)
  __shared__ float lsum[DIM];
  __shared__ float lsq[DIM];
  int b = blockIdx.x;
  int t = threadIdx.x;
  if (t < 128) sd[t] = 0;
  if (t < DIM) { lsum[t] = 0.0f; lsq[t] = 0.0f; }
  __syncthreads();
  int pbase = b * CAP;
  int cnt = gcursor[b] - pbase;
  // --- phase A: counting sort into LDS stage ---
  for (int i = t; i < cnt; i += 512)
    atomicAdd(&sd[bpart[pbase + i] >> 17], 1);
  __syncthreads();
  int deg = (t < 128) ? sd[t] : 0;
  for (int off = 1; off < 128; off <<= 1) {   // inclusive scan of degrees
    int a = (t < 128 && t >= off) ? sd[t - off] : 0;
    __syncthreads();
    if (t < 128) sd[t] += a;
    __syncthreads();
  }
  if (t < 128) cur[t] = sd[t] - deg;          // exclusive start
  __syncthreads();
  for (int i = t; i < cnt; i += 512) {
    int v = bpart[pbase + i];
    int p = atomicAdd(&cur[v >> 17], 1);
    stage[p] = v & 0x1FFFF;
  }
  __syncthreads();
  // --- phase B: gather neighbor rows (bf16) into hbuf ---
  {
    int part = t & 15;
    int ng = t >> 4;                          // 0..31
#pragma unroll 1
    for (int pass = 0; pass < 4; ++pass) {
      int nl = ng + pass * 32;                // local node 0..127
      int e0 = (nl == 0) ? 0 : sd[nl - 1];
      int e1 = sd[nl];
      float4 a0 = make_float4(0.f, 0.f, 0.f, 0.f);
      float4 a1 = a0, a2 = a0, a3 = a0;
      int e = e0;
      for (; e + 4 <= e1; e += 4) {
        int s0 = stage[e + 0];
        int s1 = stage[e + 1];
        int s2 = stage[e + 2];
        int s3 = stage[e + 3];
        ushort4 u0 = ((const ushort4*)(xb + (size_t)s0 * DIM))[part];
        ushort4 u1 = ((const ushort4*)(xb + (size_t)s1 * DIM))[part];
        ushort4 u2 = ((const ushort4*)(xb + (size_t)s2 * DIM))[part];
        ushort4 u3 = ((const ushort4*)(xb + (size_t)s3 * DIM))[part];
        a0.x += bf16_to_f32(u0.x); a0.y += bf16_to_f32(u0.y);
        a0.z += bf16_to_f32(u0.z); a0.w += bf16_to_f32(u0.w);
        a1.x += bf16_to_f32(u1.x); a1.y += bf16_to_f32(u1.y);
        a1.z += bf16_to_f32(u1.z); a1.w += bf16_to_f32(u1.w);
        a2.x += bf16_to_f32(u2.x); a2.y += bf16_to_f32(u2.y);
        a2.z += bf16_to_f32(u2.z); a2.w += bf16_to_f32(u2.w);
        a3.x += bf16_to_f32(u3.x); a3.y += bf16_to_f32(u3.y);
        a3.z += bf16_to_f32(u3.z); a3.w += bf16_to_f32(u3.w);
      }
      for (; e < e1; ++e) {
        int s = stage[e];
        ushort4 u = ((const ushort4*)(xb + (size_t)s * DIM))[part];
        a0.x += bf16_to_f32(u.x); a0.y += bf16_to_f32(u.y);
        a0.z += bf16_to_f32(u.z); a0.w += bf16_to_f32(u.w);
      }
      float4 acc;
      acc.x = (a0.x + a1.x) + (a2.x + a3.x);
      acc.y = (a0.y + a1.y) + (a2.y + a3.y);
      acc.z = (a0.z + a1.z) + (a2.z + a3.z);
      acc.w = (a0.w + a1.w) + (a2.w + a3.w);
      *(float4*)&hbuf[nl * HP + part * 4] = acc;
    }
  }
  __syncthreads();
  // --- phase C: MFMA GEMM1 per wave + h1 store + BN stat partials ---
  {
    int wave = t >> 6;
    int lane = t & 63;
    int tile = b * 8 + wave;
    if (tile < NTILES) {                      // N % 16 == 0, tiles fully valid
      int q = lane >> 4;
      int r16 = lane & 15;
      float onep = 1.0f + epsp[0];
      s16x8 bf[8];
#pragma unroll
      for (int f = 0; f < 8; ++f)
        bf[f] = ((const s16x8*)Wp)[f * 64 + lane];
      int lrow = wave * 16 + r16;             // local row in hbuf
      int grow = b * 128 + lrow;              // global row
      const s16x8* xrow = (const s16x8*)(xb + (size_t)grow * DIM);
      f32x4 acc[4] = {{0.f,0.f,0.f,0.f},{0.f,0.f,0.f,0.f},
                      {0.f,0.f,0.f,0.f},{0.f,0.f,0.f,0.f}};
#pragma unroll
      for (int kk = 0; kk < 2; ++kk) {
        s16x8 xv = xrow[kk * 4 + q];
        const float* hb = &hbuf[lrow * HP + kk * 32 + q * 8];
        float4 h0 = *(const float4*)hb;
        float4 h4 = *(const float4*)(hb + 4);
        s16x8 a;
        a[0] = (short)bf16_rne(fmaf(onep, bf16_to_f32((unsigned short)xv[0]), h0.x));
        a[1] = (short)bf16_rne(fmaf(onep, bf16_to_f32((unsigned short)xv[1]), h0.y));
        a[2] = (short)bf16_rne(fmaf(onep, bf16_to_f32((unsigned short)xv[2]), h0.z));
        a[3] = (short)bf16_rne(fmaf(onep, bf16_to_f32((unsigned short)xv[3]), h0.w));
        a[4] = (short)bf16_rne(fmaf(onep, bf16_to_f32((unsigned short)xv[4]), h4.x));
        a[5] = (short)bf16_rne(fmaf(onep, bf16_to_f32((unsigned short)xv[5]), h4.y));
        a[6] = (short)bf16_rne(fmaf(onep, bf16_to_f32((unsigned short)xv[6]), h4.z));
        a[7] = (short)bf16_rne(fmaf(onep, bf16_to_f32((unsigned short)xv[7]), h4.w));
#pragma unroll
        for (int nt = 0; nt < 4; ++nt)
          acc[nt] = __builtin_amdgcn_mfma_f32_16x16x32_bf16(
              a, bf[kk * 4 + nt], acc[nt], 0, 0, 0);
      }
      int orow = tile * 16 + q * 4;
#pragma unroll
      for (int nt = 0; nt < 4; ++nt) {
        int col = nt * 16 + r16;
        float bb = b1[col];
        float sl = 0.0f, ql = 0.0f;
#pragma unroll
        for (int r = 0; r < 4; ++r) {
          float v = acc[nt][r] + bb;
          h1[(size_t)(orow + r) * DIM + col] = v;
          sl += v;
          ql = fmaf(v, v, ql);
        }
        // reduce the 4 quads (same col) -> lanes 0..15
        sl += __shfl_down(sl, 32); ql += __shfl_down(ql, 32);
        sl += __shfl_down(sl, 16); ql += __shfl_down(ql, 16);
        if (q == 0) {
          atomicAdd(&lsum[col], sl);
          atomicAdd(&lsq[col], ql);
        }
      }
    }
  }
  __syncthreads();
  if (t < DIM) {
    atomicAdd(&sums[t], lsum[t]);
    atomicAdd(&sumsq[t], lsq[t]);
  }
}

// ---------------- fused2 (MFMA): out = relu(bn(h1)) @ W2 + b2 ---------------
__global__ __launch_bounds__(256) void fused2_kernel(
    const float* __restrict__ h1, float* __restrict__ out,
    const unsigned short* __restrict__ Wp, const float* __restrict__ b2,
    const float* __restrict__ gamma, const float* __restrict__ beta,
    const float* __restrict__ sums, const float* __restrict__ sumsq) {
  __shared__ float sc_s[DIM];
  __shared__ float sh_s[DIM];
  int t = threadIdx.x;
  if (t < DIM) {
    float invN = 1.0f / (float)NNODES;
    float m = sums[t] * invN;
    float v = fmaf(-m, m, sumsq[t] * invN);
    float sc = gamma[t] * rsqrtf(v + 1e-5f);
    sc_s[t] = sc;
    sh_s[t] = fmaf(-m, sc, beta[t]);
  }
  __syncthreads();
  int wave = t >> 6;
  int lane = t & 63;
  int tile = blockIdx.x * 4 + wave;
  if (tile >= NTILES) return;
  int q = lane >> 4;
  int r16 = lane & 15;
  s16x8 bf[8];
#pragma unroll
  for (int f = 0; f < 8; ++f)
    bf[f] = ((const s16x8*)Wp)[f * 64 + lane];
  int arow = tile * 16 + r16;
  const float* hr = h1 + (size_t)arow * DIM + q * 8;
  f32x4 acc[4] = {{0.f,0.f,0.f,0.f},{0.f,0.f,0.f,0.f},
                  {0.f,0.f,0.f,0.f},{0.f,0.f,0.f,0.f}};
#pragma unroll
  for (int kk = 0; kk < 2; ++kk) {
    int kbase = kk * 32 + q * 8;
    float4 hv0 = *(const float4*)(hr + kk * 32);
    float4 hv1 = *(const float4*)(hr + kk * 32 + 4);
    float4 sc0 = *(const float4*)(sc_s + kbase);
    float4 sc1 = *(const float4*)(sc_s + kbase + 4);
    float4 sh0 = *(const float4*)(sh_s + kbase);
    float4 sh1 = *(const float4*)(sh_s + kbase + 4);
    s16x8 a;
    a[0] = (short)bf16_rne(fmaxf(fmaf(hv0.x, sc0.x, sh0.x), 0.f));
    a[1] = (short)bf16_rne(fmaxf(fmaf(hv0.y, sc0.y, sh0.y), 0.f));
    a[2] = (short)bf16_rne(fmaxf(fmaf(hv0.z, sc0.z, sh0.z), 0.f));
    a[3] = (short)bf16_rne(fmaxf(fmaf(hv0.w, sc0.w, sh0.w), 0.f));
    a[4] = (short)bf16_rne(fmaxf(fmaf(hv1.x, sc1.x, sh1.x), 0.f));
    a[5] = (short)bf16_rne(fmaxf(fmaf(hv1.y, sc1.y, sh1.y), 0.f));
    a[6] = (short)bf16_rne(fmaxf(fmaf(hv1.z, sc1.z, sh1.z), 0.f));
    a[7] = (short)bf16_rne(fmaxf(fmaf(hv1.w, sc1.w, sh1.w), 0.f));
#pragma unroll
    for (int nt = 0; nt < 4; ++nt)
      acc[nt] = __builtin_amdgcn_mfma_f32_16x16x32_bf16(
          a, bf[kk * 4 + nt], acc[nt], 0, 0, 0);
  }
  int orow = tile * 16 + q * 4;
#pragma unroll
  for (int nt = 0; nt < 4; ++nt) {
    int col = nt * 16 + r16;
    float bb = b2[col];
#pragma unroll
    for (int r = 0; r < 4; ++r)
      out[(size_t)(orow + r) * DIM + col] = acc[nt][r] + bb;
  }
}

extern "C" void kernel_launch(void* const* d_in, const int* in_sizes, int n_in,
                              void* d_out, int out_size, void* d_ws, size_t ws_size,
                              hipStream_t stream) {
  (void)in_sizes; (void)n_in; (void)out_size; (void)ws_size;
  const float* x     = (const float*)d_in[0];
  const int*   ei    = (const int*)d_in[1];
  const float* eps   = (const float*)d_in[2];
  const float* W1    = (const float*)d_in[3];
  const float* b1    = (const float*)d_in[4];
  const float* gamma = (const float*)d_in[5];
  const float* beta  = (const float*)d_in[6];
  const float* W2    = (const float*)d_in[7];
  const float* b2    = (const float*)d_in[8];
  float* outp = (float*)d_out;

  const int N = NNODES;

  // workspace (~25.7 MB): h1 lives where agg used to
  float* h1      = (float*)d_ws;                 // N*64 f32
  float* sums    = h1 + (size_t)N * DIM;         // 64 f32 (zeroed in initpack)
  float* sumsq   = sums + DIM;                   // 64 f32 (zeroed in initpack)
  int*   gcursor = (int*)(sumsq + DIM);          // NB int
  unsigned short* Wp1 = (unsigned short*)(gcursor + ((NB + 1) & ~1)); // 4096 bf16
  unsigned short* Wp2 = Wp1 + 4096;                                   // 4096 bf16
  // d_out scratch (dead before fused2 overwrites it):
  //   bpart:  NB*CAP ints = 12.41 MB ; xb: N*DIM bf16 = 12.80 MB  (25.21<=25.6)
  int*            bpart = (int*)d_out;
  unsigned short* xb    = (unsigned short*)d_out + (size_t)NB * CAP * 2;

  initpack_kernel <<<1, 1024, 0, stream>>>(gcursor, sums, W1, W2, Wp1, Wp2);
  convert_kernel  <<<N * DIM / 4 / 256, 256, 0, stream>>>(x, xb);
  partition_kernel<<<NPB, 1024, 0, stream>>>(ei, gcursor, bpart);
  mega_kernel     <<<NB, 512, 0, stream>>>(bpart, gcursor, xb, h1,
                                           Wp1, b1, eps, sums, sumsq);
  fused2_kernel   <<<(NTILES + 3) / 4, 256, 0, stream>>>(h1, outp, Wp2, b2,
                                                         gamma, beta, sums, sumsq);
}

// Round 10
// 183.072 us; speedup vs baseline: 1.5028x; 1.0357x over previous
//
#include <hip/hip_runtime.h>

#define NNODES 100000
#define NEDGES 1600000
#define DIM 64
#define NB 782          // buckets of 128 nodes (dst >> 7); 782*128 = 100096
#define NPB 256         // partition blocks
#define CHUNK 6250      // edges per partition block (NPB * CHUNK == NEDGES)
#define CAP 3968        // padded slots per bucket (mean 2048, sigma 45 -> 42 sigma)
#define HP 68           // hbuf pitch (64 + 4 pad)
#define NTILES 6250     // 100000 / 16 row-tiles

typedef __attribute__((ext_vector_type(4))) float f32x4;
typedef __attribute__((ext_vector_type(8))) short s16x8;   // 8 bf16 in 4 VGPRs

__device__ __forceinline__ unsigned short bf16_rne(float f) {
  unsigned u = __float_as_uint(f);
  u += 0x7FFF + ((u >> 16) & 1);
  return (unsigned short)(u >> 16);
}
__device__ __forceinline__ float bf16_to_f32(unsigned short h) {
  return __uint_as_float(((unsigned)h) << 16);
}

// ---------------- P0: x->bf16 convert; block 0 also inits + packs W ---------
// B-frag for mfma_f32_16x16x32_bf16: lane L holds B[k=8*(L>>4)+j][n=L&15].
__global__ __launch_bounds__(256) void prep_kernel(
    const float* __restrict__ x, unsigned short* __restrict__ xb,
    int* __restrict__ gcursor, float* __restrict__ sums,
    const float* __restrict__ W1, const float* __restrict__ W2,
    unsigned short* __restrict__ Wp1, unsigned short* __restrict__ Wp2) {
  int i = blockIdx.x * 256 + threadIdx.x;   // N*DIM/4 threads exactly
  float4 v = ((const float4*)x)[i];
  ushort4 o;
  o.x = bf16_rne(v.x); o.y = bf16_rne(v.y);
  o.z = bf16_rne(v.z); o.w = bf16_rne(v.w);
  ((ushort4*)xb)[i] = o;
  if (blockIdx.x == 0) {
    int t = threadIdx.x;
    for (int b = t; b < NB; b += 256) gcursor[b] = b * CAP;
    if (t < 2 * DIM) sums[t] = 0.0f;        // sums[64] + sumsq[64] contiguous
    if (t < 128) {
      int lane = t & 63;
      const float* W = (t >= 64) ? W2 : W1;
      unsigned short* Wp = (t >= 64) ? Wp2 : Wp1;
      int q = lane >> 4, n16 = lane & 15;
#pragma unroll
      for (int f = 0; f < 8; ++f) {
        int kk = f >> 2, nt = f & 3;
#pragma unroll
        for (int j = 0; j < 8; ++j) {
          int k = kk * 32 + q * 8 + j;
          int n = nt * 16 + n16;
          Wp[f * 512 + lane * 8 + j] = bf16_rne(W[k * DIM + n]);
        }
      }
    }
  }
}

// ---------------- P1: partition edges, LDS-staged -> COALESCED flush --------
__global__ __launch_bounds__(1024) void partition_kernel(
    const int* __restrict__ ei, int* __restrict__ gcursor,
    int* __restrict__ bpart) {
  __shared__ int sd[1024];                  // hist -> inclusive scan
  __shared__ int delta[1024];               // global_base - local_start
  __shared__ int lcur[1024];                // local scatter cursor
  __shared__ int stage[CHUNK];              // bucket-sorted packed edges
  __shared__ unsigned short sbuck[CHUNK];   // bucket id per staged slot
  int t = threadIdx.x;
  sd[t] = 0;
  __syncthreads();
  int base = blockIdx.x * CHUNK;
  // pass 1: histogram
  for (int i = t; i < CHUNK; i += 1024)
    atomicAdd(&sd[ei[NEDGES + base + i] >> 7], 1);
  __syncthreads();
  int v = sd[t];
  for (int off = 1; off < 1024; off <<= 1) {  // inclusive scan
    int a = (t >= off) ? sd[t - off] : 0;
    __syncthreads();
    sd[t] += a;
    __syncthreads();
  }
  int excl = sd[t] - v;                     // local run start
  delta[t] = (v ? atomicAdd(&gcursor[t], v) : 0) - excl;
  lcur[t] = excl;
  __syncthreads();
  // pass 2: scatter into LDS, bucket-sorted
  for (int i = t; i < CHUNK; i += 1024) {
    int s = ei[base + i];
    int d = ei[NEDGES + base + i];
    int b = d >> 7;
    int p = atomicAdd(&lcur[b], 1);
    stage[p] = ((d & 127) << 17) | s;       // src < 2^17, dlow bits 17..23
    sbuck[p] = (unsigned short)b;
  }
  __syncthreads();
  // flush: consecutive i -> consecutive global addresses within each run
  for (int i = t; i < CHUNK; i += 1024)
    bpart[delta[sbuck[i]] + i] = stage[i];
}

// ---------------- P2 MEGA: sort + gather + GEMM1 + BN-stats partials --------
// block = one bucket of 128 nodes (8 MFMA row-tiles), 512 threads (8 waves).
__global__ __launch_bounds__(512) void mega_kernel(
    const int* __restrict__ bpart, const int* __restrict__ gcursor,
    const unsigned short* __restrict__ xb, float* __restrict__ h1,
    const unsigned short* __restrict__ Wp, const float* __restrict__ b1,
    const float* __restrict__ epsp,
    float* __restrict__ sums, float* __restrict__ sumsq) {
  __shared__ int sd[128];        // per-node degree -> inclusive scan
  __shared__ int cur[128];       // scatter cursors
  __shared__ int stage[CAP];     // sorted src list for this bucket
  __shared__ float hbuf[128 * HP];  // gathered agg rows (padded pitch)
  __shared__ float lsum[DIM];
  __shared__ float lsq[DIM];
  int b = blockIdx.x;
  int t = threadIdx.x;
  if (t < 128) sd[t] = 0;
  if (t < DIM) { lsum[t] = 0.0f; lsq[t] = 0.0f; }
  __syncthreads();
  int pbase = b * CAP;
  int cnt = gcursor[b] - pbase;
  // --- phase A: counting sort into LDS stage ---
  for (int i = t; i < cnt; i += 512)
    atomicAdd(&sd[bpart[pbase + i] >> 17], 1);
  __syncthreads();
  int deg = (t < 128) ? sd[t] : 0;
  for (int off = 1; off < 128; off <<= 1) {   // inclusive scan of degrees
    int a = (t < 128 && t >= off) ? sd[t - off] : 0;
    __syncthreads();
    if (t < 128) sd[t] += a;
    __syncthreads();
  }
  if (t < 128) cur[t] = sd[t] - deg;          // exclusive start
  __syncthreads();
  for (int i = t; i < cnt; i += 512) {
    int v = bpart[pbase + i];
    int p = atomicAdd(&cur[v >> 17], 1);
    stage[p] = v & 0x1FFFF;
  }
  __syncthreads();
  // --- phase B: gather neighbor rows (bf16) into hbuf ---
  {
    int part = t & 15;
    int ng = t >> 4;                          // 0..31
#pragma unroll 1
    for (int pass = 0; pass < 4; ++pass) {
      int nl = ng + pass * 32;                // local node 0..127
      int e0 = (nl == 0) ? 0 : sd[nl - 1];
      int e1 = sd[nl];
      float4 a0 = make_float4(0.f, 0.f, 0.f, 0.f);
      float4 a1 = a0, a2 = a0, a3 = a0;
      int e = e0;
      for (; e + 4 <= e1; e += 4) {
        int s0 = stage[e + 0];
        int s1 = stage[e + 1];
        int s2 = stage[e + 2];
        int s3 = stage[e + 3];
        ushort4 u0 = ((const ushort4*)(xb + (size_t)s0 * DIM))[part];
        ushort4 u1 = ((const ushort4*)(xb + (size_t)s1 * DIM))[part];
        ushort4 u2 = ((const ushort4*)(xb + (size_t)s2 * DIM))[part];
        ushort4 u3 = ((const ushort4*)(xb + (size_t)s3 * DIM))[part];
        a0.x += bf16_to_f32(u0.x); a0.y += bf16_to_f32(u0.y);
        a0.z += bf16_to_f32(u0.z); a0.w += bf16_to_f32(u0.w);
        a1.x += bf16_to_f32(u1.x); a1.y += bf16_to_f32(u1.y);
        a1.z += bf16_to_f32(u1.z); a1.w += bf16_to_f32(u1.w);
        a2.x += bf16_to_f32(u2.x); a2.y += bf16_to_f32(u2.y);
        a2.z += bf16_to_f32(u2.z); a2.w += bf16_to_f32(u2.w);
        a3.x += bf16_to_f32(u3.x); a3.y += bf16_to_f32(u3.y);
        a3.z += bf16_to_f32(u3.z); a3.w += bf16_to_f32(u3.w);
      }
      for (; e < e1; ++e) {
        int s = stage[e];
        ushort4 u = ((const ushort4*)(xb + (size_t)s * DIM))[part];
        a0.x += bf16_to_f32(u.x); a0.y += bf16_to_f32(u.y);
        a0.z += bf16_to_f32(u.z); a0.w += bf16_to_f32(u.w);
      }
      float4 acc;
      acc.x = (a0.x + a1.x) + (a2.x + a3.x);
      acc.y = (a0.y + a1.y) + (a2.y + a3.y);
      acc.z = (a0.z + a1.z) + (a2.z + a3.z);
      acc.w = (a0.w + a1.w) + (a2.w + a3.w);
      *(float4*)&hbuf[nl * HP + part * 4] = acc;
    }
  }
  __syncthreads();
  // --- phase C: MFMA GEMM1 per wave + h1 store + BN stat partials ---
  {
    int wave = t >> 6;
    int lane = t & 63;
    int tile = b * 8 + wave;
    if (tile < NTILES) {
      int q = lane >> 4;
      int r16 = lane & 15;
      float onep = 1.0f + epsp[0];
      s16x8 bf[8];
#pragma unroll
      for (int f = 0; f < 8; ++f)
        bf[f] = ((const s16x8*)Wp)[f * 64 + lane];
      int lrow = wave * 16 + r16;             // local row in hbuf
      int grow = b * 128 + lrow;              // global row
      const s16x8* xrow = (const s16x8*)(xb + (size_t)grow * DIM);
      f32x4 acc[4] = {{0.f,0.f,0.f,0.f},{0.f,0.f,0.f,0.f},
                      {0.f,0.f,0.f,0.f},{0.f,0.f,0.f,0.f}};
#pragma unroll
      for (int kk = 0; kk < 2; ++kk) {
        s16x8 xv = xrow[kk * 4 + q];
        const float* hb = &hbuf[lrow * HP + kk * 32 + q * 8];
        float4 h0 = *(const float4*)hb;
        float4 h4 = *(const float4*)(hb + 4);
        s16x8 a;
        a[0] = (short)bf16_rne(fmaf(onep, bf16_to_f32((unsigned short)xv[0]), h0.x));
        a[1] = (short)bf16_rne(fmaf(onep, bf16_to_f32((unsigned short)xv[1]), h0.y));
        a[2] = (short)bf16_rne(fmaf(onep, bf16_to_f32((unsigned short)xv[2]), h0.z));
        a[3] = (short)bf16_rne(fmaf(onep, bf16_to_f32((unsigned short)xv[3]), h0.w));
        a[4] = (short)bf16_rne(fmaf(onep, bf16_to_f32((unsigned short)xv[4]), h4.x));
        a[5] = (short)bf16_rne(fmaf(onep, bf16_to_f32((unsigned short)xv[5]), h4.y));
        a[6] = (short)bf16_rne(fmaf(onep, bf16_to_f32((unsigned short)xv[6]), h4.z));
        a[7] = (short)bf16_rne(fmaf(onep, bf16_to_f32((unsigned short)xv[7]), h4.w));
#pragma unroll
        for (int nt = 0; nt < 4; ++nt)
          acc[nt] = __builtin_amdgcn_mfma_f32_16x16x32_bf16(
              a, bf[kk * 4 + nt], acc[nt], 0, 0, 0);
      }
      int orow = tile * 16 + q * 4;
#pragma unroll
      for (int nt = 0; nt < 4; ++nt) {
        int col = nt * 16 + r16;
        float bb = b1[col];
        float sl = 0.0f, ql = 0.0f;
#pragma unroll
        for (int r = 0; r < 4; ++r) {
          float v = acc[nt][r] + bb;
          h1[(size_t)(orow + r) * DIM + col] = v;
          sl += v;
          ql = fmaf(v, v, ql);
        }
        sl += __shfl_down(sl, 32); ql += __shfl_down(ql, 32);
        sl += __shfl_down(sl, 16); ql += __shfl_down(ql, 16);
        if (q == 0) {
          atomicAdd(&lsum[col], sl);
          atomicAdd(&lsq[col], ql);
        }
      }
    }
  }
  __syncthreads();
  if (t < DIM) {
    atomicAdd(&sums[t], lsum[t]);
    atomicAdd(&sumsq[t], lsq[t]);
  }
}

// ---------------- fused2 (MFMA): out = relu(bn(h1)) @ W2 + b2 ---------------
__global__ __launch_bounds__(256) void fused2_kernel(
    const float* __restrict__ h1, float* __restrict__ out,
    const unsigned short* __restrict__ Wp, const float* __restrict__ b2,
    const float* __restrict__ gamma, const float* __restrict__ beta,
    const float* __restrict__ sums, const float* __restrict__ sumsq) {
  __shared__ float sc_s[DIM];
  __shared__ float sh_s[DIM];
  int t = threadIdx.x;
  if (t < DIM) {
    float invN = 1.0f / (float)NNODES;
    float m = sums[t] * invN;
    float v = fmaf(-m, m, sumsq[t] * invN);
    float sc = gamma[t] * rsqrtf(v + 1e-5f);
    sc_s[t] = sc;
    sh_s[t] = fmaf(-m, sc, beta[t]);
  }
  __syncthreads();
  int wave = t >> 6;
  int lane = t & 63;
  int tile = blockIdx.x * 4 + wave;
  if (tile >= NTILES) return;
  int q = lane >> 4;
  int r16 = lane & 15;
  s16x8 bf[8];
#pragma unroll
  for (int f = 0; f < 8; ++f)
    bf[f] = ((const s16x8*)Wp)[f * 64 + lane];
  int arow = tile * 16 + r16;
  const float* hr = h1 + (size_t)arow * DIM + q * 8;
  f32x4 acc[4] = {{0.f,0.f,0.f,0.f},{0.f,0.f,0.f,0.f},
                  {0.f,0.f,0.f,0.f},{0.f,0.f,0.f,0.f}};
#pragma unroll
  for (int kk = 0; kk < 2; ++kk) {
    int kbase = kk * 32 + q * 8;
    float4 hv0 = *(const float4*)(hr + kk * 32);
    float4 hv1 = *(const float4*)(hr + kk * 32 + 4);
    float4 sc0 = *(const float4*)(sc_s + kbase);
    float4 sc1 = *(const float4*)(sc_s + kbase + 4);
    float4 sh0 = *(const float4*)(sh_s + kbase);
    float4 sh1 = *(const float4*)(sh_s + kbase + 4);
    s16x8 a;
    a[0] = (short)bf16_rne(fmaxf(fmaf(hv0.x, sc0.x, sh0.x), 0.f));
    a[1] = (short)bf16_rne(fmaxf(fmaf(hv0.y, sc0.y, sh0.y), 0.f));
    a[2] = (short)bf16_rne(fmaxf(fmaf(hv0.z, sc0.z, sh0.z), 0.f));
    a[3] = (short)bf16_rne(fmaxf(fmaf(hv0.w, sc0.w, sh0.w), 0.f));
    a[4] = (short)bf16_rne(fmaxf(fmaf(hv1.x, sc1.x, sh1.x), 0.f));
    a[5] = (short)bf16_rne(fmaxf(fmaf(hv1.y, sc1.y, sh1.y), 0.f));
    a[6] = (short)bf16_rne(fmaxf(fmaf(hv1.z, sc1.z, sh1.z), 0.f));
    a[7] = (short)bf16_rne(fmaxf(fmaf(hv1.w, sc1.w, sh1.w), 0.f));
#pragma unroll
    for (int nt = 0; nt < 4; ++nt)
      acc[nt] = __builtin_amdgcn_mfma_f32_16x16x32_bf16(
          a, bf[kk * 4 + nt], acc[nt], 0, 0, 0);
  }
  int orow = tile * 16 + q * 4;
#pragma unroll
  for (int nt = 0; nt < 4; ++nt) {
    int col = nt * 16 + r16;
    float bb = b2[col];
#pragma unroll
    for (int r = 0; r < 4; ++r)
      out[(size_t)(orow + r) * DIM + col] = acc[nt][r] + bb;
  }
}

extern "C" void kernel_launch(void* const* d_in, const int* in_sizes, int n_in,
                              void* d_out, int out_size, void* d_ws, size_t ws_size,
                              hipStream_t stream) {
  (void)in_sizes; (void)n_in; (void)out_size; (void)ws_size;
  const float* x     = (const float*)d_in[0];
  const int*   ei    = (const int*)d_in[1];
  const float* eps   = (const float*)d_in[2];
  const float* W1    = (const float*)d_in[3];
  const float* b1    = (const float*)d_in[4];
  const float* gamma = (const float*)d_in[5];
  const float* beta  = (const float*)d_in[6];
  const float* W2    = (const float*)d_in[7];
  const float* b2    = (const float*)d_in[8];
  float* outp = (float*)d_out;

  const int N = NNODES;

  // workspace (~25.7 MB)
  float* h1      = (float*)d_ws;                 // N*64 f32
  float* sums    = h1 + (size_t)N * DIM;         // 64 f32 (zeroed in prep)
  float* sumsq   = sums + DIM;                   // 64 f32 (zeroed in prep)
  int*   gcursor = (int*)(sumsq + DIM);          // NB int
  unsigned short* Wp1 = (unsigned short*)(gcursor + ((NB + 1) & ~1)); // 4096 bf16
  unsigned short* Wp2 = Wp1 + 4096;                                   // 4096 bf16
  // d_out scratch (dead before fused2 overwrites it):
  //   bpart: NB*CAP ints = 12.41 MB ; xb: N*DIM bf16 = 12.80 MB (25.21<=25.6)
  int*            bpart = (int*)d_out;
  unsigned short* xb    = (unsigned short*)d_out + (size_t)NB * CAP * 2;

  prep_kernel     <<<N * DIM / 4 / 256, 256, 0, stream>>>(x, xb, gcursor, sums,
                                                          W1, W2, Wp1, Wp2);
  partition_kernel<<<NPB, 1024, 0, stream>>>(ei, gcursor, bpart);
  mega_kernel     <<<NB, 512, 0, stream>>>(bpart, gcursor, xb, h1,
                                           Wp1, b1, eps, sums, sumsq);
  fused2_kernel   <<<(NTILES + 3) / 4, 256, 0, stream>>>(h1, outp, Wp2, b2,
                                                         gamma, beta, sums, sumsq);
}

// Round 11
// 174.426 us; speedup vs baseline: 1.5773x; 1.0496x over previous
//
#include <hip/hip_runtime.h>

#define NNODES 100000
#define NEDGES 1600000
#define DIM 64
#define NB 782          // buckets of 128 nodes (dst >> 7); 782*128 = 100096
#define NPB 256         // partition blocks
#define CHUNK 6250      // edges per partition block (NPB * CHUNK == NEDGES)
#define CAP 3968        // padded slots per bucket (mean 2048, sigma 45 -> 42 sigma)
#define HP 68           // hbuf pitch in SHORTS (64 + 4 pad; 8B-aligned rows)
#define NTILES 6250     // 100000 / 16 row-tiles

typedef __attribute__((ext_vector_type(4))) float f32x4;
typedef __attribute__((ext_vector_type(8))) short s16x8;   // 8 bf16 in 4 VGPRs

__device__ __forceinline__ unsigned short bf16_rne(float f) {
  unsigned u = __float_as_uint(f);
  u += 0x7FFF + ((u >> 16) & 1);
  return (unsigned short)(u >> 16);
}
__device__ __forceinline__ float bf16_to_f32(unsigned short h) {
  return __uint_as_float(((unsigned)h) << 16);
}

// ---------------- P0: x->bf16 convert; block 0 also inits + packs W ---------
// B-frag for mfma_f32_16x16x32_bf16: lane L holds B[k=8*(L>>4)+j][n=L&15].
__global__ __launch_bounds__(256) void prep_kernel(
    const float* __restrict__ x, unsigned short* __restrict__ xb,
    int* __restrict__ gcursor, float* __restrict__ sums,
    const float* __restrict__ W1, const float* __restrict__ W2,
    unsigned short* __restrict__ Wp1, unsigned short* __restrict__ Wp2) {
  int i = blockIdx.x * 256 + threadIdx.x;   // N*DIM/4 threads exactly
  float4 v = ((const float4*)x)[i];
  ushort4 o;
  o.x = bf16_rne(v.x); o.y = bf16_rne(v.y);
  o.z = bf16_rne(v.z); o.w = bf16_rne(v.w);
  ((ushort4*)xb)[i] = o;
  if (blockIdx.x == 0) {
    int t = threadIdx.x;
    for (int b = t; b < NB; b += 256) gcursor[b] = b * CAP;
    if (t < 2 * DIM) sums[t] = 0.0f;        // sums[64] + sumsq[64] contiguous
    if (t < 128) {
      int lane = t & 63;
      const float* W = (t >= 64) ? W2 : W1;
      unsigned short* Wp = (t >= 64) ? Wp2 : Wp1;
      int q = lane >> 4, n16 = lane & 15;
#pragma unroll
      for (int f = 0; f < 8; ++f) {
        int kk = f >> 2, nt = f & 3;
#pragma unroll
        for (int j = 0; j < 8; ++j) {
          int k = kk * 32 + q * 8 + j;
          int n = nt * 16 + n16;
          Wp[f * 512 + lane * 8 + j] = bf16_rne(W[k * DIM + n]);
        }
      }
    }
  }
}

// ---------------- P1: partition edges, LDS-staged -> COALESCED flush --------
__global__ __launch_bounds__(1024) void partition_kernel(
    const int* __restrict__ ei, int* __restrict__ gcursor,
    int* __restrict__ bpart) {
  __shared__ int sd[1024];                  // hist -> inclusive scan
  __shared__ int delta[1024];               // global_base - local_start
  __shared__ int lcur[1024];                // local scatter cursor
  __shared__ int stage[CHUNK];              // bucket-sorted packed edges
  __shared__ unsigned short sbuck[CHUNK];   // bucket id per staged slot
  int t = threadIdx.x;
  sd[t] = 0;
  __syncthreads();
  int base = blockIdx.x * CHUNK;
  // pass 1: histogram
  for (int i = t; i < CHUNK; i += 1024)
    atomicAdd(&sd[ei[NEDGES + base + i] >> 7], 1);
  __syncthreads();
  int v = sd[t];
  for (int off = 1; off < 1024; off <<= 1) {  // inclusive scan
    int a = (t >= off) ? sd[t - off] : 0;
    __syncthreads();
    sd[t] += a;
    __syncthreads();
  }
  int excl = sd[t] - v;                     // local run start
  delta[t] = (v ? atomicAdd(&gcursor[t], v) : 0) - excl;
  lcur[t] = excl;
  __syncthreads();
  // pass 2: scatter into LDS, bucket-sorted
  for (int i = t; i < CHUNK; i += 1024) {
    int s = ei[base + i];
    int d = ei[NEDGES + base + i];
    int b = d >> 7;
    int p = atomicAdd(&lcur[b], 1);
    stage[p] = ((d & 127) << 17) | s;       // src < 2^17, dlow bits 17..23
    sbuck[p] = (unsigned short)b;
  }
  __syncthreads();
  // flush: consecutive i -> consecutive global addresses within each run
  for (int i = t; i < CHUNK; i += 1024)
    bpart[delta[sbuck[i]] + i] = stage[i];
}

// ---------------- P2 MEGA: sort + gather + GEMM1 + BN-stats partials --------
// block = one bucket of 128 nodes (8 MFMA row-tiles), 512 threads (8 waves).
// hbuf in bf16: LDS ~35 KB -> 4 blocks/CU for cross-block phase overlap.
__global__ __launch_bounds__(512) void mega_kernel(
    const int* __restrict__ bpart, const int* __restrict__ gcursor,
    const unsigned short* __restrict__ xb, float* __restrict__ h1,
    const unsigned short* __restrict__ Wp, const float* __restrict__ b1,
    const float* __restrict__ epsp,
    float* __restrict__ sums, float* __restrict__ sumsq) {
  __shared__ int sd[128];        // per-node degree -> inclusive scan
  __shared__ int cur[128];       // scatter cursors
  __shared__ int stage[CAP];     // sorted src list for this bucket
  __shared__ unsigned short hbuf[128 * HP];  // gathered agg rows, bf16
  __shared__ float lsum[DIM];
  __shared__ float lsq[DIM];
  int b = blockIdx.x;
  int t = threadIdx.x;
  if (t < 128) sd[t] = 0;
  if (t < DIM) { lsum[t] = 0.0f; lsq[t] = 0.0f; }
  __syncthreads();
  int pbase = b * CAP;
  int cnt = gcursor[b] - pbase;
  // --- phase A: counting sort into LDS stage ---
  for (int i = t; i < cnt; i += 512)
    atomicAdd(&sd[bpart[pbase + i] >> 17], 1);
  __syncthreads();
  int deg = (t < 128) ? sd[t] : 0;
  for (int off = 1; off < 128; off <<= 1) {   // inclusive scan of degrees
    int a = (t < 128 && t >= off) ? sd[t - off] : 0;
    __syncthreads();
    if (t < 128) sd[t] += a;
    __syncthreads();
  }
  if (t < 128) cur[t] = sd[t] - deg;          // exclusive start
  __syncthreads();
  for (int i = t; i < cnt; i += 512) {
    int v = bpart[pbase + i];
    int p = atomicAdd(&cur[v >> 17], 1);
    stage[p] = v & 0x1FFFF;
  }
  __syncthreads();
  // --- phase B: gather neighbor rows (bf16) into hbuf (bf16) ---
  {
    int part = t & 15;
    int ng = t >> 4;                          // 0..31
#pragma unroll 1
    for (int pass = 0; pass < 4; ++pass) {
      int nl = ng + pass * 32;                // local node 0..127
      int e0 = (nl == 0) ? 0 : sd[nl - 1];
      int e1 = sd[nl];
      float4 a0 = make_float4(0.f, 0.f, 0.f, 0.f);
      float4 a1 = a0, a2 = a0, a3 = a0;
      int e = e0;
      for (; e + 4 <= e1; e += 4) {           // 4 independent 8B loads in flight
        int s0 = stage[e + 0];
        int s1 = stage[e + 1];
        int s2 = stage[e + 2];
        int s3 = stage[e + 3];
        ushort4 u0 = ((const ushort4*)(xb + (size_t)s0 * DIM))[part];
        ushort4 u1 = ((const ushort4*)(xb + (size_t)s1 * DIM))[part];
        ushort4 u2 = ((const ushort4*)(xb + (size_t)s2 * DIM))[part];
        ushort4 u3 = ((const ushort4*)(xb + (size_t)s3 * DIM))[part];
        a0.x += bf16_to_f32(u0.x); a0.y += bf16_to_f32(u0.y);
        a0.z += bf16_to_f32(u0.z); a0.w += bf16_to_f32(u0.w);
        a1.x += bf16_to_f32(u1.x); a1.y += bf16_to_f32(u1.y);
        a1.z += bf16_to_f32(u1.z); a1.w += bf16_to_f32(u1.w);
        a2.x += bf16_to_f32(u2.x); a2.y += bf16_to_f32(u2.y);
        a2.z += bf16_to_f32(u2.z); a2.w += bf16_to_f32(u2.w);
        a3.x += bf16_to_f32(u3.x); a3.y += bf16_to_f32(u3.y);
        a3.z += bf16_to_f32(u3.z); a3.w += bf16_to_f32(u3.w);
      }
      for (; e < e1; ++e) {
        int s = stage[e];
        ushort4 u = ((const ushort4*)(xb + (size_t)s * DIM))[part];
        a0.x += bf16_to_f32(u.x); a0.y += bf16_to_f32(u.y);
        a0.z += bf16_to_f32(u.z); a0.w += bf16_to_f32(u.w);
      }
      ushort4 o;
      o.x = bf16_rne((a0.x + a1.x) + (a2.x + a3.x));
      o.y = bf16_rne((a0.y + a1.y) + (a2.y + a3.y));
      o.z = bf16_rne((a0.z + a1.z) + (a2.z + a3.z));
      o.w = bf16_rne((a0.w + a1.w) + (a2.w + a3.w));
      *(ushort4*)&hbuf[nl * HP + part * 4] = o;
    }
  }
  __syncthreads();
  // --- phase C: MFMA GEMM1 per wave + h1 store + BN stat partials ---
  {
    int wave = t >> 6;
    int lane = t & 63;
    int tile = b * 8 + wave;
    if (tile < NTILES) {
      int q = lane >> 4;
      int r16 = lane & 15;
      float onep = 1.0f + epsp[0];
      s16x8 bf[8];
#pragma unroll
      for (int f = 0; f < 8; ++f)
        bf[f] = ((const s16x8*)Wp)[f * 64 + lane];
      int lrow = wave * 16 + r16;             // local row in hbuf
      int grow = b * 128 + lrow;              // global row
      const s16x8* xrow = (const s16x8*)(xb + (size_t)grow * DIM);
      f32x4 acc[4] = {{0.f,0.f,0.f,0.f},{0.f,0.f,0.f,0.f},
                      {0.f,0.f,0.f,0.f},{0.f,0.f,0.f,0.f}};
#pragma unroll
      for (int kk = 0; kk < 2; ++kk) {
        s16x8 xv = xrow[kk * 4 + q];
        const unsigned short* hb = &hbuf[lrow * HP + kk * 32 + q * 8];
        ushort4 h0 = *(const ushort4*)hb;       // 8B-aligned LDS reads,
        ushort4 h4 = *(const ushort4*)(hb + 4); // 2-way bank alias = free
        s16x8 a;
        a[0] = (short)bf16_rne(fmaf(onep, bf16_to_f32((unsigned short)xv[0]), bf16_to_f32(h0.x)));
        a[1] = (short)bf16_rne(fmaf(onep, bf16_to_f32((unsigned short)xv[1]), bf16_to_f32(h0.y)));
        a[2] = (short)bf16_rne(fmaf(onep, bf16_to_f32((unsigned short)xv[2]), bf16_to_f32(h0.z)));
        a[3] = (short)bf16_rne(fmaf(onep, bf16_to_f32((unsigned short)xv[3]), bf16_to_f32(h0.w)));
        a[4] = (short)bf16_rne(fmaf(onep, bf16_to_f32((unsigned short)xv[4]), bf16_to_f32(h4.x)));
        a[5] = (short)bf16_rne(fmaf(onep, bf16_to_f32((unsigned short)xv[5]), bf16_to_f32(h4.y)));
        a[6] = (short)bf16_rne(fmaf(onep, bf16_to_f32((unsigned short)xv[6]), bf16_to_f32(h4.z)));
        a[7] = (short)bf16_rne(fmaf(onep, bf16_to_f32((unsigned short)xv[7]), bf16_to_f32(h4.w)));
#pragma unroll
        for (int nt = 0; nt < 4; ++nt)
          acc[nt] = __builtin_amdgcn_mfma_f32_16x16x32_bf16(
              a, bf[kk * 4 + nt], acc[nt], 0, 0, 0);
      }
      int orow = tile * 16 + q * 4;
#pragma unroll
      for (int nt = 0; nt < 4; ++nt) {
        int col = nt * 16 + r16;
        float bb = b1[col];
        float sl = 0.0f, ql = 0.0f;
#pragma unroll
        for (int r = 0; r < 4; ++r) {
          float v = acc[nt][r] + bb;
          h1[(size_t)(orow + r) * DIM + col] = v;
          sl += v;
          ql = fmaf(v, v, ql);
        }
        sl += __shfl_down(sl, 32); ql += __shfl_down(ql, 32);
        sl += __shfl_down(sl, 16); ql += __shfl_down(ql, 16);
        if (q == 0) {
          atomicAdd(&lsum[col], sl);
          atomicAdd(&lsq[col], ql);
        }
      }
    }
  }
  __syncthreads();
  if (t < DIM) {
    atomicAdd(&sums[t], lsum[t]);
    atomicAdd(&sumsq[t], lsq[t]);
  }
}

// ---------------- fused2 (MFMA): out = relu(bn(h1)) @ W2 + b2 ---------------
__global__ __launch_bounds__(256) void fused2_kernel(
    const float* __restrict__ h1, float* __restrict__ out,
    const unsigned short* __restrict__ Wp, const float* __restrict__ b2,
    const float* __restrict__ gamma, const float* __restrict__ beta,
    const float* __restrict__ sums, const float* __restrict__ sumsq) {
  __shared__ float sc_s[DIM];
  __shared__ float sh_s[DIM];
  int t = threadIdx.x;
  if (t < DIM) {
    float invN = 1.0f / (float)NNODES;
    float m = sums[t] * invN;
    float v = fmaf(-m, m, sumsq[t] * invN);
    float sc = gamma[t] * rsqrtf(v + 1e-5f);
    sc_s[t] = sc;
    sh_s[t] = fmaf(-m, sc, beta[t]);
  }
  __syncthreads();
  int wave = t >> 6;
  int lane = t & 63;
  int tile = blockIdx.x * 4 + wave;
  if (tile >= NTILES) return;
  int q = lane >> 4;
  int r16 = lane & 15;
  s16x8 bf[8];
#pragma unroll
  for (int f = 0; f < 8; ++f)
    bf[f] = ((const s16x8*)Wp)[f * 64 + lane];
  int arow = tile * 16 + r16;
  const float* hr = h1 + (size_t)arow * DIM + q * 8;
  f32x4 acc[4] = {{0.f,0.f,0.f,0.f},{0.f,0.f,0.f,0.f},
                  {0.f,0.f,0.f,0.f},{0.f,0.f,0.f,0.f}};
#pragma unroll
  for (int kk = 0; kk < 2; ++kk) {
    int kbase = kk * 32 + q * 8;
    float4 hv0 = *(const float4*)(hr + kk * 32);
    float4 hv1 = *(const float4*)(hr + kk * 32 + 4);
    float4 sc0 = *(const float4*)(sc_s + kbase);
    float4 sc1 = *(const float4*)(sc_s + kbase + 4);
    float4 sh0 = *(const float4*)(sh_s + kbase);
    float4 sh1 = *(const float4*)(sh_s + kbase + 4);
    s16x8 a;
    a[0] = (short)bf16_rne(fmaxf(fmaf(hv0.x, sc0.x, sh0.x), 0.f));
    a[1] = (short)bf16_rne(fmaxf(fmaf(hv0.y, sc0.y, sh0.y), 0.f));
    a[2] = (short)bf16_rne(fmaxf(fmaf(hv0.z, sc0.z, sh0.z), 0.f));
    a[3] = (short)bf16_rne(fmaxf(fmaf(hv0.w, sc0.w, sh0.w), 0.f));
    a[4] = (short)bf16_rne(fmaxf(fmaf(hv1.x, sc1.x, sh1.x), 0.f));
    a[5] = (short)bf16_rne(fmaxf(fmaf(hv1.y, sc1.y, sh1.y), 0.f));
    a[6] = (short)bf16_rne(fmaxf(fmaf(hv1.z, sc1.z, sh1.z), 0.f));
    a[7] = (short)bf16_rne(fmaxf(fmaf(hv1.w, sc1.w, sh1.w), 0.f));
#pragma unroll
    for (int nt = 0; nt < 4; ++nt)
      acc[nt] = __builtin_amdgcn_mfma_f32_16x16x32_bf16(
          a, bf[kk * 4 + nt], acc[nt], 0, 0, 0);
  }
  int orow = tile * 16 + q * 4;
#pragma unroll
  for (int nt = 0; nt < 4; ++nt) {
    int col = nt * 16 + r16;
    float bb = b2[col];
#pragma unroll
    for (int r = 0; r < 4; ++r)
      out[(size_t)(orow + r) * DIM + col] = acc[nt][r] + bb;
  }
}

extern "C" void kernel_launch(void* const* d_in, const int* in_sizes, int n_in,
                              void* d_out, int out_size, void* d_ws, size_t ws_size,
                              hipStream_t stream) {
  (void)in_sizes; (void)n_in; (void)out_size; (void)ws_size;
  const float* x     = (const float*)d_in[0];
  const int*   ei    = (const int*)d_in[1];
  const float* eps   = (const float*)d_in[2];
  const float* W1    = (const float*)d_in[3];
  const float* b1    = (const float*)d_in[4];
  const float* gamma = (const float*)d_in[5];
  const float* beta  = (const float*)d_in[6];
  const float* W2    = (const float*)d_in[7];
  const float* b2    = (const float*)d_in[8];
  float* outp = (float*)d_out;

  const int N = NNODES;

  // workspace (~25.7 MB)
  float* h1      = (float*)d_ws;                 // N*64 f32
  float* sums    = h1 + (size_t)N * DIM;         // 64 f32 (zeroed in prep)
  float* sumsq   = sums + DIM;                   // 64 f32 (zeroed in prep)
  int*   gcursor = (int*)(sumsq + DIM);          // NB int
  unsigned short* Wp1 = (unsigned short*)(gcursor + ((NB + 1) & ~1)); // 4096 bf16
  unsigned short* Wp2 = Wp1 + 4096;                                   // 4096 bf16
  // d_out scratch (dead before fused2 overwrites it):
  //   bpart: NB*CAP ints = 12.41 MB ; xb: N*DIM bf16 = 12.80 MB (25.21<=25.6)
  int*            bpart = (int*)d_out;
  unsigned short* xb    = (unsigned short*)d_out + (size_t)NB * CAP * 2;

  prep_kernel     <<<N * DIM / 4 / 256, 256, 0, stream>>>(x, xb, gcursor, sums,
                                                          W1, W2, Wp1, Wp2);
  partition_kernel<<<NPB, 1024, 0, stream>>>(ei, gcursor, bpart);
  mega_kernel     <<<NB, 512, 0, stream>>>(bpart, gcursor, xb, h1,
                                           Wp1, b1, eps, sums, sumsq);
  fused2_kernel   <<<(NTILES + 3) / 4, 256, 0, stream>>>(h1, outp, Wp2, b2,
                                                         gamma, beta, sums, sumsq);
}